// Round 2
// baseline (2624.162 us; speedup 1.0000x reference)
//
#include <hip/hip_runtime.h>
#include <hip/hip_bf16.h>

// All reference tensors are float32 (jnp.float32) — fp32 I/O throughout.

constexpr int BATCH = 2;
constexpr int CINCH = 512;
constexpr int CDCH  = 256;
constexpr int CQCH  = 32;
constexpr int IMG   = 64;
constexpr int NPIX  = 4096;   // 64*64

// ---------------------------------------------------------------------------
// Kernel 1: 3x3 conv (512->256, pad 1) + BatchNorm + PReLU, fp32 out.
// Block: 256 thr = 4 oc-groups x (8x8 thread grid, 2x2 px each) -> 16oc x 16x16 tile
// grid: (16 spatial tiles, 16 oc tiles, B)
// ---------------------------------------------------------------------------
__global__ __launch_bounds__(256)
void conv3_bn_prelu(const float* __restrict__ x, const float* __restrict__ w,
                    const float* __restrict__ cb, const float* __restrict__ bg,
                    const float* __restrict__ bb, const float* __restrict__ bm,
                    const float* __restrict__ bv, const float* __restrict__ pr,
                    float* __restrict__ out)
{
    __shared__ float xs[8][18][20];    // 8 ic x 18x18 patch (col pad 20)
    __shared__ float wsh[8][16][12];   // 8 ic x 16 oc x 9 taps (pad 12)

    const int t    = threadIdx.x;
    const int tile = blockIdx.x;
    const int oc0  = blockIdx.y * 16;
    const int b    = blockIdx.z;
    const int ty0  = (tile >> 2) * 16;
    const int tx0  = (tile & 3) * 16;
    const int ocg  = t >> 6;          // 0..3
    const int sy   = (t >> 3) & 7;
    const int sx   = t & 7;

    float acc[4][2][2];
#pragma unroll
    for (int o = 0; o < 4; ++o)
#pragma unroll
        for (int dy = 0; dy < 2; ++dy)
#pragma unroll
            for (int dx = 0; dx < 2; ++dx) acc[o][dy][dx] = 0.f;

    const float* xb = x + (long)b * CINCH * NPIX;

    for (int ic0 = 0; ic0 < CINCH; ic0 += 8) {
        // stage x patch (zeros outside image)
        for (int idx = t; idx < 8 * 324; idx += 256) {
            int icl = idx / 324; int r = idx - icl * 324;
            int py = r / 18;     int px = r - py * 18;
            int gy = ty0 - 1 + py, gx = tx0 - 1 + px;
            float v = 0.f;
            if (gy >= 0 && gy < IMG && gx >= 0 && gx < IMG)
                v = xb[(ic0 + icl) * NPIX + gy * IMG + gx];
            xs[icl][py][px] = v;
        }
        // stage weights
        for (int idx = t; idx < 8 * 16 * 9; idx += 256) {
            int icl = idx / 144; int r = idx - icl * 144;
            int ocl = r / 9;     int tap = r - ocl * 9;
            wsh[icl][ocl][tap] = w[((oc0 + ocl) * CINCH + ic0 + icl) * 9 + tap];
        }
        __syncthreads();

#pragma unroll
        for (int icl = 0; icl < 8; ++icl) {
            float xr[4][4];
#pragma unroll
            for (int r4 = 0; r4 < 4; ++r4) {
                const float2* xp = (const float2*)&xs[icl][2 * sy + r4][2 * sx];
                float2 a = xp[0], bq = xp[1];
                xr[r4][0] = a.x; xr[r4][1] = a.y; xr[r4][2] = bq.x; xr[r4][3] = bq.y;
            }
#pragma unroll
            for (int o = 0; o < 4; ++o) {
                const float* wp = &wsh[icl][ocg * 4 + o][0];
                float w0 = wp[0], w1 = wp[1], w2 = wp[2], w3 = wp[3], w4 = wp[4],
                      w5 = wp[5], w6 = wp[6], w7 = wp[7], w8 = wp[8];
#pragma unroll
                for (int dy = 0; dy < 2; ++dy)
#pragma unroll
                    for (int dx = 0; dx < 2; ++dx) {
                        float s = acc[o][dy][dx];
                        s = fmaf(w0, xr[dy    ][dx], s);
                        s = fmaf(w1, xr[dy    ][dx + 1], s);
                        s = fmaf(w2, xr[dy    ][dx + 2], s);
                        s = fmaf(w3, xr[dy + 1][dx], s);
                        s = fmaf(w4, xr[dy + 1][dx + 1], s);
                        s = fmaf(w5, xr[dy + 1][dx + 2], s);
                        s = fmaf(w6, xr[dy + 2][dx], s);
                        s = fmaf(w7, xr[dy + 2][dx + 1], s);
                        s = fmaf(w8, xr[dy + 2][dx + 2], s);
                        acc[o][dy][dx] = s;
                    }
            }
        }
        __syncthreads();
    }

    // BN + PReLU epilogue
    float a_pr = pr[0];
#pragma unroll
    for (int o = 0; o < 4; ++o) {
        int oc = oc0 + ocg * 4 + o;
        float scale = bg[oc] * rsqrtf(bv[oc] + 1e-5f);
        float shift = bb[oc] - bm[oc] * scale;
        float cbo = cb[oc];
#pragma unroll
        for (int dy = 0; dy < 2; ++dy)
#pragma unroll
            for (int dx = 0; dx < 2; ++dx) {
                float y = acc[o][dy][dx] + cbo;
                y = y * scale + shift;
                y = (y > 0.f) ? y : a_pr * y;
                int py = ty0 + 2 * sy + dy, px = tx0 + 2 * sx + dx;
                out[(b * CDCH + oc) * NPIX + py * IMG + px] = y;
            }
    }
}

// ---------------------------------------------------------------------------
// Kernel 2: 1x1 conv GEMM. C[M,4096] = A[M,256] @ Bmat[256,4096] + bias
// mode 0: fp32 out to Cbase.  mode 1: out = acc + bias + resid, fp32 store.
// Block tile 32M x 128N, K-chunk 32, 4x4 per thread. grid: (32, M/32, B)
// ---------------------------------------------------------------------------
__global__ __launch_bounds__(256)
void gemm1x1(const float* __restrict__ A, const float* __restrict__ Bbase, long strideB,
             const float* __restrict__ bias,
             float* __restrict__ Cbase, long strideC,
             const float* __restrict__ residBase, long strideR,
             float* __restrict__ obase, long strideO,
             int M, int mode)
{
    __shared__ float As[32][36];    // [k][m] pad 36
    __shared__ float Bs[32][128];   // [k][n]

    const int t  = threadIdx.x;
    const int n0 = blockIdx.x * 128;
    const int m0 = blockIdx.y * 32;
    const int b  = blockIdx.z;
    const float* Bm = Bbase + b * strideB;
    const int tm = t >> 5, tn = t & 31;

    float acc[4][4];
#pragma unroll
    for (int i = 0; i < 4; ++i)
#pragma unroll
        for (int j = 0; j < 4; ++j) acc[i][j] = 0.f;

    for (int kc = 0; kc < 256; kc += 32) {
        // stage A transposed (32m x 32k), each thread 4 floats
        {
            int ml = t >> 3, kq = t & 7;
            float4 a4 = *(const float4*)&A[(m0 + ml) * 256 + kc + kq * 4];
            As[kq * 4 + 0][ml] = a4.x;
            As[kq * 4 + 1][ml] = a4.y;
            As[kq * 4 + 2][ml] = a4.z;
            As[kq * 4 + 3][ml] = a4.w;
        }
        // stage B (32k x 128n) as float4
        for (int idx = t; idx < 1024; idx += 256) {
            int kl = idx >> 5, n4 = idx & 31;
            *(float4*)&Bs[kl][n4 * 4] = *(const float4*)&Bm[(kc + kl) * NPIX + n0 + n4 * 4];
        }
        __syncthreads();

#pragma unroll
        for (int kk = 0; kk < 32; ++kk) {
            float4 a4 = *(const float4*)&As[kk][tm * 4];
            float4 b4 = *(const float4*)&Bs[kk][tn * 4];
            float av[4] = {a4.x, a4.y, a4.z, a4.w};
            float bw[4] = {b4.x, b4.y, b4.z, b4.w};
#pragma unroll
            for (int i = 0; i < 4; ++i)
#pragma unroll
                for (int j = 0; j < 4; ++j) acc[i][j] = fmaf(av[i], bw[j], acc[i][j]);
        }
        __syncthreads();
    }

    if (mode == 0) {
        float* C = Cbase + b * strideC;
#pragma unroll
        for (int i = 0; i < 4; ++i) {
            int m = m0 + tm * 4 + i;
            float bi = bias[m];
            float4 o4 = make_float4(acc[i][0] + bi, acc[i][1] + bi,
                                    acc[i][2] + bi, acc[i][3] + bi);
            *(float4*)&C[(long)m * NPIX + n0 + tn * 4] = o4;
        }
    } else {
        const float* R = residBase + b * strideR;
        float* O = obase + b * strideO;
#pragma unroll
        for (int i = 0; i < 4; ++i) {
            int m = m0 + tm * 4 + i;
            float bi = bias[m];
            long off = (long)m * NPIX + n0 + tn * 4;
            float4 r4 = *(const float4*)&R[off];
            float4 o4 = make_float4(acc[i][0] + bi + r4.x, acc[i][1] + bi + r4.y,
                                    acc[i][2] + bi + r4.z, acc[i][3] + bi + r4.w);
            *(float4*)&O[off] = o4;
        }
    }
}

// ---------------------------------------------------------------------------
// Kernel 3: attention row stats. S[i,j] = sum_q Q[q,i]*K[q,j] (unscaled).
// Computes rowmax m_i and 1/l_i (l = sum_j exp(S-m)). Block: 64 rows, all j.
// grid: (64 i-tiles, B)
// ---------------------------------------------------------------------------
__global__ __launch_bounds__(256)
void attn_stats(const float* __restrict__ qbase, const float* __restrict__ kbase,
                float* __restrict__ rmbase, float* __restrict__ rlbase)
{
    __shared__ float Qs[32][64];
    __shared__ float Ks[32][64];
    __shared__ float redm[16][64];
    __shared__ float redl[16][64];

    const int t  = threadIdx.x;
    const int i0 = blockIdx.x * 64;
    const int b  = blockIdx.y;
    const float* q = qbase + b * CQCH * NPIX;
    const float* k = kbase + b * CQCH * NPIX;

    for (int idx = t; idx < 512; idx += 256) {
        int ql = idx >> 4, i4 = idx & 15;
        *(float4*)&Qs[ql][i4 * 4] = *(const float4*)&q[ql * NPIX + i0 + i4 * 4];
    }

    const int ig = t & 15, jg = t >> 4;
    float mr[4], lr[4];
#pragma unroll
    for (int a = 0; a < 4; ++a) { mr[a] = -3.0e38f; lr[a] = 0.f; }

    for (int j0 = 0; j0 < NPIX; j0 += 64) {
        __syncthreads();
        for (int idx = t; idx < 512; idx += 256) {
            int ql = idx >> 4, j4 = idx & 15;
            *(float4*)&Ks[ql][j4 * 4] = *(const float4*)&k[ql * NPIX + j0 + j4 * 4];
        }
        __syncthreads();

        float s[4][4];
#pragma unroll
        for (int a = 0; a < 4; ++a)
#pragma unroll
            for (int c = 0; c < 4; ++c) s[a][c] = 0.f;
#pragma unroll
        for (int qq = 0; qq < 32; ++qq) {
            float4 qa = *(const float4*)&Qs[qq][ig * 4];
            float4 kb = *(const float4*)&Ks[qq][jg * 4];
            float qv[4] = {qa.x, qa.y, qa.z, qa.w};
            float kv[4] = {kb.x, kb.y, kb.z, kb.w};
#pragma unroll
            for (int a = 0; a < 4; ++a)
#pragma unroll
                for (int c = 0; c < 4; ++c) s[a][c] = fmaf(qv[a], kv[c], s[a][c]);
        }
#pragma unroll
        for (int a = 0; a < 4; ++a) {
            float mx = fmaxf(fmaxf(s[a][0], s[a][1]), fmaxf(s[a][2], s[a][3]));
            float mn = fmaxf(mr[a], mx);
            lr[a] = lr[a] * __expf(mr[a] - mn)
                  + __expf(s[a][0] - mn) + __expf(s[a][1] - mn)
                  + __expf(s[a][2] - mn) + __expf(s[a][3] - mn);
            mr[a] = mn;
        }
    }
    __syncthreads();
#pragma unroll
    for (int a = 0; a < 4; ++a) { redm[jg][ig * 4 + a] = mr[a]; redl[jg][ig * 4 + a] = lr[a]; }
    __syncthreads();
    if (t < 64) {
        float mf = -3.0e38f;
#pragma unroll
        for (int g = 0; g < 16; ++g) mf = fmaxf(mf, redm[g][t]);
        float lf = 0.f;
#pragma unroll
        for (int g = 0; g < 16; ++g) lf += redl[g][t] * __expf(redm[g][t] - mf);
        float* rm = rmbase + b * NPIX;
        float* rl = rlbase + b * NPIX;
        rm[i0 + t] = mf;
        rl[i0 + t] = 1.f / lf;
    }
}

// ---------------------------------------------------------------------------
// Kernel 4: PV with recomputed P. z[c,i] = gamma * sum_j P[i,j] V[c,j] + conv[c,i]
// P[i,j] = exp(S[i,j]-m_i) * (1/l_i). Block: 64c x 64i tile, j chunks of 32.
// grid: (64 i-tiles, 4 c-tiles, B)
// ---------------------------------------------------------------------------
__global__ __launch_bounds__(256)
void attn_pv(const float* __restrict__ qbase, const float* __restrict__ kbase,
             const float* __restrict__ vbase, const float* __restrict__ convbase,
             float* __restrict__ zbase, const float* __restrict__ rmbase,
             const float* __restrict__ rlbase, const float* __restrict__ gp)
{
    __shared__ float Qs[32][64];
    __shared__ float Ks[32][32];
    __shared__ float Pt[32][68];   // [j][i] pad 68
    __shared__ float Vt[32][68];   // [j][c] pad 68
    __shared__ float mls[64], rls[64];

    const int t  = threadIdx.x;
    const int i0 = blockIdx.x * 64;
    const int c0 = blockIdx.y * 64;
    const int b  = blockIdx.z;
    const float* q  = qbase + b * CQCH * NPIX;
    const float* k  = kbase + b * CQCH * NPIX;
    const float* v  = vbase + b * CDCH * NPIX;
    const float* cv = convbase + b * CDCH * NPIX;
    float* z = zbase + b * CDCH * NPIX;
    const float* rm = rmbase + b * NPIX;
    const float* rl = rlbase + b * NPIX;

    for (int idx = t; idx < 512; idx += 256) {
        int ql = idx >> 4, i4 = idx & 15;
        *(float4*)&Qs[ql][i4 * 4] = *(const float4*)&q[ql * NPIX + i0 + i4 * 4];
    }
    if (t < 64) { mls[t] = rm[i0 + t]; rls[t] = rl[i0 + t]; }

    const int igA = t & 15, jgA = t >> 4;   // phase A: 4i x 2j
    const int cg  = t & 15, ig2 = t >> 4;   // phase B: 4c x 4i

    float acc[4][4];
#pragma unroll
    for (int i = 0; i < 4; ++i)
#pragma unroll
        for (int j = 0; j < 4; ++j) acc[i][j] = 0.f;

    for (int j0 = 0; j0 < NPIX; j0 += 32) {
        __syncthreads();
        // stage K chunk [32q][32j]
        {
            int ql = t >> 3, j4 = t & 7;
            *(float4*)&Ks[ql][j4 * 4] = *(const float4*)&k[ql * NPIX + j0 + j4 * 4];
        }
        // stage V transposed [32j][64c]
        for (int idx = t; idx < 2048; idx += 256) {
            int cl = idx >> 5, jl = idx & 31;
            Vt[jl][cl] = v[(c0 + cl) * NPIX + j0 + jl];
        }
        __syncthreads();

        // phase A: S tile -> P (normalized), write transposed
        {
            float s[4][2];
#pragma unroll
            for (int a = 0; a < 4; ++a) { s[a][0] = 0.f; s[a][1] = 0.f; }
#pragma unroll
            for (int qq = 0; qq < 32; ++qq) {
                float4 qa = *(const float4*)&Qs[qq][igA * 4];
                float2 kb = *(const float2*)&Ks[qq][jgA * 2];
                float qv[4] = {qa.x, qa.y, qa.z, qa.w};
#pragma unroll
                for (int a = 0; a < 4; ++a) {
                    s[a][0] = fmaf(qv[a], kb.x, s[a][0]);
                    s[a][1] = fmaf(qv[a], kb.y, s[a][1]);
                }
            }
#pragma unroll
            for (int jj = 0; jj < 2; ++jj) {
                float4 p = make_float4(
                    __expf(s[0][jj] - mls[igA * 4 + 0]) * rls[igA * 4 + 0],
                    __expf(s[1][jj] - mls[igA * 4 + 1]) * rls[igA * 4 + 1],
                    __expf(s[2][jj] - mls[igA * 4 + 2]) * rls[igA * 4 + 2],
                    __expf(s[3][jj] - mls[igA * 4 + 3]) * rls[igA * 4 + 3]);
                *(float4*)&Pt[jgA * 2 + jj][igA * 4] = p;
            }
        }
        __syncthreads();

        // phase B: acc[c][i] += V[c,j] * P[i,j]
#pragma unroll
        for (int jl = 0; jl < 32; ++jl) {
            float4 vv = *(const float4*)&Vt[jl][cg * 4];
            float4 pp = *(const float4*)&Pt[jl][ig2 * 4];
            float va[4] = {vv.x, vv.y, vv.z, vv.w};
            float pa[4] = {pp.x, pp.y, pp.z, pp.w};
#pragma unroll
            for (int cc = 0; cc < 4; ++cc)
#pragma unroll
                for (int ii = 0; ii < 4; ++ii)
                    acc[cc][ii] = fmaf(va[cc], pa[ii], acc[cc][ii]);
        }
    }

    // epilogue: z = gamma*acc + conv
    float gamma = gp[0];
#pragma unroll
    for (int cc = 0; cc < 4; ++cc) {
        int c = c0 + cg * 4 + cc;
        const float4 cvx = *(const float4*)&cv[c * NPIX + i0 + ig2 * 4];
        float4 zo = make_float4(gamma * acc[cc][0] + cvx.x,
                                gamma * acc[cc][1] + cvx.y,
                                gamma * acc[cc][2] + cvx.z,
                                gamma * acc[cc][3] + cvx.w);
        *(float4*)&z[c * NPIX + i0 + ig2 * 4] = zo;
    }
}

// ---------------------------------------------------------------------------
// Host launcher
// ---------------------------------------------------------------------------
// ws layout (floats):
//   conv [2mod][2b][256][4096] @ 0        (4,194,304)
//   q    [2mod][2b][32][4096]  @ 4194304  (524,288)
//   k                           @ 4718592 (524,288)
//   v    [2mod][2b][256][4096] @ 5242880  (4,194,304)
//   z    [2mod][2b][256][4096] @ 9437184  (4,194,304)
//   rowm [2o][2b][4096]        @ 13631488 (16,384)
//   rowl                        @ 13647872 (16,384)
//   total 13,664,256 floats = 52.1 MiB
extern "C" void kernel_launch(void* const* d_in, const int* in_sizes, int n_in,
                              void* d_out, int out_size, void* d_ws, size_t ws_size,
                              hipStream_t stream)
{
    const float* in_rgb = (const float*)d_in[0];
    const float* in_dsm = (const float*)d_in[1];
    auto P = [&](int i) { return (const float*)d_in[i]; };

    float* ws   = (float*)d_ws;
    float* conv = ws;
    float* qb_  = ws + 4194304;
    float* kb_  = ws + 4718592;
    float* vb_  = ws + 5242880;
    float* zb_  = ws + 9437184;
    float* rmb  = ws + 13631488;
    float* rlb  = ws + 13647872;
    const long MODC = 2097152;   // per-modality stride for conv/v/z
    const long MODQ = 262144;    // per-modality stride for q/k

    // conv+bn+prelu (per modality; batch in grid.z)
    for (int mod = 0; mod < 2; ++mod) {
        int base = mod ? 18 : 2;
        const float* xin = mod ? in_dsm : in_rgb;
        conv3_bn_prelu<<<dim3(16, 16, 2), 256, 0, stream>>>(
            xin, P(base + 0), P(base + 1), P(base + 2), P(base + 3),
            P(base + 4), P(base + 5), P(base + 6), conv + mod * MODC);
    }
    // q, k, v projections
    for (int mod = 0; mod < 2; ++mod) {
        int base = mod ? 18 : 2;
        gemm1x1<<<dim3(32, 1, 2), 256, 0, stream>>>(
            P(base + 7), conv + mod * MODC, 1048576, P(base + 8),
            qb_ + mod * MODQ, 131072, nullptr, 0, nullptr, 0, 32, 0);
        gemm1x1<<<dim3(32, 1, 2), 256, 0, stream>>>(
            P(base + 9), conv + mod * MODC, 1048576, P(base + 10),
            kb_ + mod * MODQ, 131072, nullptr, 0, nullptr, 0, 32, 0);
        gemm1x1<<<dim3(32, 8, 2), 256, 0, stream>>>(
            P(base + 11), conv + mod * MODC, 1048576, P(base + 12),
            vb_ + mod * MODC, 1048576, nullptr, 0, nullptr, 0, 256, 0);
    }
    // attention row stats: output modality o uses Q from other(o), K from o
    for (int o = 0; o < 2; ++o) {
        int other = 1 - o;
        attn_stats<<<dim3(64, 2), 256, 0, stream>>>(
            qb_ + other * MODQ, kb_ + o * MODQ, rmb + o * 8192, rlb + o * 8192);
    }
    // PV + gamma-gate + conv residual -> z
    for (int o = 0; o < 2; ++o) {
        int other = 1 - o;
        int base = o ? 18 : 2;
        attn_pv<<<dim3(64, 4, 2), 256, 0, stream>>>(
            qb_ + other * MODQ, kb_ + o * MODQ, vb_ + o * MODC, conv + o * MODC,
            zb_ + o * MODC, rmb + o * 8192, rlb + o * 8192, P(base + 15));
    }
    // up projection + input residual -> fp32 out
    for (int o = 0; o < 2; ++o) {
        int base = o ? 18 : 2;
        const float* xin = o ? in_dsm : in_rgb;
        gemm1x1<<<dim3(32, 16, 2), 256, 0, stream>>>(
            P(base + 13), zb_ + o * MODC, 1048576, P(base + 14),
            nullptr, 0, xin, 2097152, (float*)d_out + (long)o * 4194304, 2097152,
            512, 1);
    }
}

// Round 3
// 1652.459 us; speedup vs baseline: 1.5880x; 1.5880x over previous
//
#include <hip/hip_runtime.h>
#include <hip/hip_bf16.h>
#include <stdint.h>

// All reference tensors are float32. Conv3x3 runs as bf16 MFMA implicit GEMM.

constexpr int CINCH = 512;
constexpr int CDCH  = 256;
constexpr int CQCH  = 32;
constexpr int IMG   = 64;
constexpr int NPIX  = 4096;   // 64*64

typedef __bf16 bf16x8 __attribute__((ext_vector_type(8)));
typedef __bf16 bf16x4 __attribute__((ext_vector_type(4)));
typedef float  f32x4  __attribute__((ext_vector_type(4)));

__device__ __forceinline__ __bf16 f2b(float f) {
    __hip_bfloat16 h = __float2bfloat16(f);
    return *reinterpret_cast<__bf16*>(&h);
}

__device__ __forceinline__ void load_lds16(const void* g, void* l) {
    __builtin_amdgcn_global_load_lds(
        (const __attribute__((address_space(1))) unsigned int*)(uintptr_t)g,
        (__attribute__((address_space(3))) unsigned int*)(uintptr_t)l,
        16, 0, 0);
}

// ---------------------------------------------------------------------------
// Prep A: weights fp32 [oc][ic][9] -> Wt bf16 [mod][tap][oc][ic]; BN tables;
// zero row. grid 2307 x 256.
// ---------------------------------------------------------------------------
__global__ __launch_bounds__(256)
void prep_w(const float* __restrict__ w_r, const float* __restrict__ w_d,
            const float* __restrict__ cb_r, const float* __restrict__ bg_r,
            const float* __restrict__ bb_r, const float* __restrict__ bm_r,
            const float* __restrict__ bv_r,
            const float* __restrict__ cb_d, const float* __restrict__ bg_d,
            const float* __restrict__ bb_d, const float* __restrict__ bm_d,
            const float* __restrict__ bv_d,
            __bf16* __restrict__ Wt, float* __restrict__ scA,
            float* __restrict__ shB, __bf16* __restrict__ zrow)
{
    const int t = threadIdx.x;
    const int blk = blockIdx.x;
    if (blk < 2304) {
        int gid = blk * 1024 + t * 4;             // element index into Wt
        int mod = gid >= 1179648;
        int o2  = gid - mod * 1179648;
        int tap = o2 >> 17;
        int r   = o2 & 131071;
        int oc  = r >> 9;
        int ic  = r & 511;
        const float* wsrc = mod ? w_d : w_r;
        long base = ((long)(oc * 512 + ic)) * 9 + tap;
        bf16x4 v;
        v.x = f2b(wsrc[base]);
        v.y = f2b(wsrc[base + 9]);
        v.z = f2b(wsrc[base + 18]);
        v.w = f2b(wsrc[base + 27]);
        *(bf16x4*)&Wt[gid] = v;
    } else if (blk == 2304) {
        unsigned short* z = (unsigned short*)zrow;
        z[t] = 0; z[t + 256] = 0;
    } else {
        int mod = blk - 2305;
        const float* cb = mod ? cb_d : cb_r;
        const float* bg = mod ? bg_d : bg_r;
        const float* bb = mod ? bb_d : bb_r;
        const float* bm = mod ? bm_d : bm_r;
        const float* bv = mod ? bv_d : bv_r;
        int oc = t;
        float sc = bg[oc] * rsqrtf(bv[oc] + 1e-5f);
        scA[mod * 256 + oc] = sc;
        shB[mod * 256 + oc] = (cb[oc] - bm[oc]) * sc + bb[oc];
    }
}

// ---------------------------------------------------------------------------
// Prep B: X fp32 [mod][b][512][4096] -> Xp bf16 [modb][4096pix][512ic]
// LDS 32x32 tile transpose. grid (128, 16, 4) x 256.
// ---------------------------------------------------------------------------
__global__ __launch_bounds__(256)
void xpose(const float* __restrict__ inr, const float* __restrict__ ind,
           __bf16* __restrict__ Xp)
{
    __shared__ float tile[32][33];
    const int t = threadIdx.x;
    const int p0 = blockIdx.x * 32;
    const int ic0 = blockIdx.y * 32;
    const int mb = blockIdx.z;
    const int mod = mb >> 1, b = mb & 1;
    const float* src = (mod ? ind : inr) + (long)b * CINCH * NPIX;

    int i = t >> 3, j4 = (t & 7) * 4;
    float4 v = *(const float4*)&src[(long)(ic0 + i) * NPIX + p0 + j4];
    tile[i][j4 + 0] = v.x; tile[i][j4 + 1] = v.y;
    tile[i][j4 + 2] = v.z; tile[i][j4 + 3] = v.w;
    __syncthreads();
    int j = t >> 3, i4 = (t & 7) * 4;
    bf16x4 o;
    o.x = f2b(tile[i4 + 0][j]);
    o.y = f2b(tile[i4 + 1][j]);
    o.z = f2b(tile[i4 + 2][j]);
    o.w = f2b(tile[i4 + 3][j]);
    *(bf16x4*)&Xp[((long)mb * NPIX + p0 + j) * 512 + ic0 + i4] = o;
}

// ---------------------------------------------------------------------------
// Conv3x3 implicit-GEMM MFMA. C[oc][pix] over K = 9 taps x 512 ic.
// Block 128oc x 128pix, 4 waves (64x64 quadrants), K-chunk 32 (one tap).
// A: Wt[mod][tap][oc][ic].  B^T: Xp[pix+shift][ic] (border rows -> zrow).
// Epilogue: BN(scale/shift folded) + PReLU, fp32 store to conv buffer.
// grid (32, 2, 4modb) x 256.
// ---------------------------------------------------------------------------
__global__ __launch_bounds__(256)
void conv_mfma(const __bf16* __restrict__ Wt, const __bf16* __restrict__ Xp,
               const __bf16* __restrict__ zrow, const float* __restrict__ scA,
               const float* __restrict__ shB, const float* __restrict__ prr,
               const float* __restrict__ prd, float* __restrict__ conv)
{
    __shared__ __bf16 As[128 * 32];   // [m][32k] rows of 64B
    __shared__ __bf16 Bs[128 * 32];   // [n][32k] rows of 64B (B^T)

    const int t = threadIdx.x;
    const int n0 = blockIdx.x * 128;
    const int m0 = blockIdx.y * 128;
    const int mb = blockIdx.z;
    const int mod = mb >> 1;

    const __bf16* Am = Wt + (long)mod * 9 * 256 * 512;
    const __bf16* Xb = Xp + (long)mb * NPIX * 512;

    const int rowa = t >> 2;          // 0..63 (staging row, issue 0)
    const int c16  = t & 3;           // 16B column within 64B row
    char* ldsA0 = (char*)As + (t >> 6) * 1024;
    char* ldsA1 = ldsA0 + 4096;
    char* ldsB0 = (char*)Bs + (t >> 6) * 1024;
    char* ldsB1 = ldsB0 + 4096;

    const int lane = t & 63;
    const int quad = lane >> 4;
    const int l15  = lane & 15;
    const int w    = t >> 6;
    const int mw0  = (w >> 1) * 64;
    const int nw0  = (w & 1) * 64;
    const char* abase = (const char*)As + (mw0 + l15) * 64 + quad * 16;
    const char* bbase = (const char*)Bs + (nw0 + l15) * 64 + quad * 16;

    f32x4 acc[4][4];
#pragma unroll
    for (int i = 0; i < 4; ++i)
#pragma unroll
        for (int j = 0; j < 4; ++j) acc[i][j] = (f32x4)0.f;

    for (int tap = 0; tap < 9; ++tap) {
        const int dy = tap / 3 - 1, dx = tap % 3 - 1;
        // per-thread staging sources for this tap
        const __bf16* srcA = Am + (long)tap * 131072 + (long)(m0 + rowa) * 512 + c16 * 8;
        const __bf16* srcB0; const __bf16* srcB1;
        bool v0, v1;
        {
            int n = n0 + rowa;
            int x = n & 63, y = n >> 6;
            v0 = !((dx == -1 && x == 0) || (dx == 1 && x == 63) ||
                   (dy == -1 && y == 0) || (dy == 1 && y == 63));
            srcB0 = v0 ? (Xb + (long)(n + dy * 64 + dx) * 512 + c16 * 8)
                       : (zrow + c16 * 8);
            n += 64; x = n & 63; y = n >> 6;
            v1 = !((dx == -1 && x == 0) || (dx == 1 && x == 63) ||
                   (dy == -1 && y == 0) || (dy == 1 && y == 63));
            srcB1 = v1 ? (Xb + (long)(n + dy * 64 + dx) * 512 + c16 * 8)
                       : (zrow + c16 * 8);
        }

        for (int ic0 = 0; ic0 < 512; ic0 += 32) {
            load_lds16(srcA + ic0, ldsA0);
            load_lds16(srcA + ic0 + 32768, ldsA1);
            load_lds16(srcB0 + (v0 ? ic0 : 0), ldsB0);
            load_lds16(srcB1 + (v1 ? ic0 : 0), ldsB1);
            __syncthreads();

            bf16x8 af[4], bfr[4];
#pragma unroll
            for (int i = 0; i < 4; ++i) af[i]  = *(const bf16x8*)(abase + i * 1024);
#pragma unroll
            for (int j = 0; j < 4; ++j) bfr[j] = *(const bf16x8*)(bbase + j * 1024);
#pragma unroll
            for (int i = 0; i < 4; ++i)
#pragma unroll
                for (int j = 0; j < 4; ++j)
                    acc[i][j] = __builtin_amdgcn_mfma_f32_16x16x32_bf16(
                        af[i], bfr[j], acc[i][j], 0, 0, 0);
            __syncthreads();
        }
    }

    // epilogue: BN + PReLU, fp32 store
    const float alpha = (mod ? prd : prr)[0];
    float* outp = conv + (long)mb * 256 * NPIX;
#pragma unroll
    for (int i = 0; i < 4; ++i) {
#pragma unroll
        for (int r = 0; r < 4; ++r) {
            int oc = m0 + mw0 + 16 * i + quad * 4 + r;
            float sc = scA[mod * 256 + oc];
            float sh = shB[mod * 256 + oc];
            float* orow = outp + (long)oc * NPIX;
#pragma unroll
            for (int j = 0; j < 4; ++j) {
                int n = n0 + nw0 + 16 * j + l15;
                float y = acc[i][j][r] * sc + sh;
                y = (y > 0.f) ? y : alpha * y;
                orow[n] = y;
            }
        }
    }
}

// ---------------------------------------------------------------------------
// 1x1 conv GEMM (fp32 vector). C[M,4096] = A[M,256] @ Bmat[256,4096] + bias
// mode 0: fp32 out. mode 1: out = acc + bias + resid.
// ---------------------------------------------------------------------------
__global__ __launch_bounds__(256)
void gemm1x1(const float* __restrict__ A, const float* __restrict__ Bbase, long strideB,
             const float* __restrict__ bias,
             float* __restrict__ Cbase, long strideC,
             const float* __restrict__ residBase, long strideR,
             float* __restrict__ obase, long strideO,
             int M, int mode)
{
    __shared__ float As[32][36];
    __shared__ float Bs[32][128];

    const int t  = threadIdx.x;
    const int n0 = blockIdx.x * 128;
    const int m0 = blockIdx.y * 32;
    const int b  = blockIdx.z;
    const float* Bm = Bbase + b * strideB;
    const int tm = t >> 5, tn = t & 31;

    float acc[4][4];
#pragma unroll
    for (int i = 0; i < 4; ++i)
#pragma unroll
        for (int j = 0; j < 4; ++j) acc[i][j] = 0.f;

    for (int kc = 0; kc < 256; kc += 32) {
        {
            int ml = t >> 3, kq = t & 7;
            float4 a4 = *(const float4*)&A[(m0 + ml) * 256 + kc + kq * 4];
            As[kq * 4 + 0][ml] = a4.x;
            As[kq * 4 + 1][ml] = a4.y;
            As[kq * 4 + 2][ml] = a4.z;
            As[kq * 4 + 3][ml] = a4.w;
        }
        for (int idx = t; idx < 1024; idx += 256) {
            int kl = idx >> 5, n4 = idx & 31;
            *(float4*)&Bs[kl][n4 * 4] = *(const float4*)&Bm[(kc + kl) * NPIX + n0 + n4 * 4];
        }
        __syncthreads();

#pragma unroll
        for (int kk = 0; kk < 32; ++kk) {
            float4 a4 = *(const float4*)&As[kk][tm * 4];
            float4 b4 = *(const float4*)&Bs[kk][tn * 4];
            float av[4] = {a4.x, a4.y, a4.z, a4.w};
            float bw[4] = {b4.x, b4.y, b4.z, b4.w};
#pragma unroll
            for (int i = 0; i < 4; ++i)
#pragma unroll
                for (int j = 0; j < 4; ++j) acc[i][j] = fmaf(av[i], bw[j], acc[i][j]);
        }
        __syncthreads();
    }

    if (mode == 0) {
        float* C = Cbase + b * strideC;
#pragma unroll
        for (int i = 0; i < 4; ++i) {
            int m = m0 + tm * 4 + i;
            float bi = bias[m];
            float4 o4 = make_float4(acc[i][0] + bi, acc[i][1] + bi,
                                    acc[i][2] + bi, acc[i][3] + bi);
            *(float4*)&C[(long)m * NPIX + n0 + tn * 4] = o4;
        }
    } else {
        const float* R = residBase + b * strideR;
        float* O = obase + b * strideO;
#pragma unroll
        for (int i = 0; i < 4; ++i) {
            int m = m0 + tm * 4 + i;
            float bi = bias[m];
            long off = (long)m * NPIX + n0 + tn * 4;
            float4 r4 = *(const float4*)&R[off];
            float4 o4 = make_float4(acc[i][0] + bi + r4.x, acc[i][1] + bi + r4.y,
                                    acc[i][2] + bi + r4.z, acc[i][3] + bi + r4.w);
            *(float4*)&O[off] = o4;
        }
    }
}

// ---------------------------------------------------------------------------
// Attention row stats (unscaled S = Q^T K over 32 q-channels).
// ---------------------------------------------------------------------------
__global__ __launch_bounds__(256)
void attn_stats(const float* __restrict__ qbase, const float* __restrict__ kbase,
                float* __restrict__ rmbase, float* __restrict__ rlbase)
{
    __shared__ float Qs[32][64];
    __shared__ float Ks[32][64];
    __shared__ float redm[16][64];
    __shared__ float redl[16][64];

    const int t  = threadIdx.x;
    const int i0 = blockIdx.x * 64;
    const int b  = blockIdx.y;
    const float* q = qbase + b * CQCH * NPIX;
    const float* k = kbase + b * CQCH * NPIX;

    for (int idx = t; idx < 512; idx += 256) {
        int ql = idx >> 4, i4 = idx & 15;
        *(float4*)&Qs[ql][i4 * 4] = *(const float4*)&q[ql * NPIX + i0 + i4 * 4];
    }

    const int ig = t & 15, jg = t >> 4;
    float mr[4], lr[4];
#pragma unroll
    for (int a = 0; a < 4; ++a) { mr[a] = -3.0e38f; lr[a] = 0.f; }

    for (int j0 = 0; j0 < NPIX; j0 += 64) {
        __syncthreads();
        for (int idx = t; idx < 512; idx += 256) {
            int ql = idx >> 4, j4 = idx & 15;
            *(float4*)&Ks[ql][j4 * 4] = *(const float4*)&k[ql * NPIX + j0 + j4 * 4];
        }
        __syncthreads();

        float s[4][4];
#pragma unroll
        for (int a = 0; a < 4; ++a)
#pragma unroll
            for (int c = 0; c < 4; ++c) s[a][c] = 0.f;
#pragma unroll
        for (int qq = 0; qq < 32; ++qq) {
            float4 qa = *(const float4*)&Qs[qq][ig * 4];
            float4 kb = *(const float4*)&Ks[qq][jg * 4];
            float qv[4] = {qa.x, qa.y, qa.z, qa.w};
            float kv[4] = {kb.x, kb.y, kb.z, kb.w};
#pragma unroll
            for (int a = 0; a < 4; ++a)
#pragma unroll
                for (int c = 0; c < 4; ++c) s[a][c] = fmaf(qv[a], kv[c], s[a][c]);
        }
#pragma unroll
        for (int a = 0; a < 4; ++a) {
            float mx = fmaxf(fmaxf(s[a][0], s[a][1]), fmaxf(s[a][2], s[a][3]));
            float mn = fmaxf(mr[a], mx);
            lr[a] = lr[a] * __expf(mr[a] - mn)
                  + __expf(s[a][0] - mn) + __expf(s[a][1] - mn)
                  + __expf(s[a][2] - mn) + __expf(s[a][3] - mn);
            mr[a] = mn;
        }
    }
    __syncthreads();
#pragma unroll
    for (int a = 0; a < 4; ++a) { redm[jg][ig * 4 + a] = mr[a]; redl[jg][ig * 4 + a] = lr[a]; }
    __syncthreads();
    if (t < 64) {
        float mf = -3.0e38f;
#pragma unroll
        for (int g = 0; g < 16; ++g) mf = fmaxf(mf, redm[g][t]);
        float lf = 0.f;
#pragma unroll
        for (int g = 0; g < 16; ++g) lf += redl[g][t] * __expf(redm[g][t] - mf);
        float* rm = rmbase + b * NPIX;
        float* rl = rlbase + b * NPIX;
        rm[i0 + t] = mf;
        rl[i0 + t] = 1.f / lf;
    }
}

// ---------------------------------------------------------------------------
// PV with recomputed P. z = gamma * (V P^T) + conv.
// ---------------------------------------------------------------------------
__global__ __launch_bounds__(256)
void attn_pv(const float* __restrict__ qbase, const float* __restrict__ kbase,
             const float* __restrict__ vbase, const float* __restrict__ convbase,
             float* __restrict__ zbase, const float* __restrict__ rmbase,
             const float* __restrict__ rlbase, const float* __restrict__ gp)
{
    __shared__ float Qs[32][64];
    __shared__ float Ks[32][32];
    __shared__ float Pt[32][68];
    __shared__ float Vt[32][68];
    __shared__ float mls[64], rls[64];

    const int t  = threadIdx.x;
    const int i0 = blockIdx.x * 64;
    const int c0 = blockIdx.y * 64;
    const int b  = blockIdx.z;
    const float* q  = qbase + b * CQCH * NPIX;
    const float* k  = kbase + b * CQCH * NPIX;
    const float* v  = vbase + b * CDCH * NPIX;
    const float* cv = convbase + b * CDCH * NPIX;
    float* z = zbase + b * CDCH * NPIX;
    const float* rm = rmbase + b * NPIX;
    const float* rl = rlbase + b * NPIX;

    for (int idx = t; idx < 512; idx += 256) {
        int ql = idx >> 4, i4 = idx & 15;
        *(float4*)&Qs[ql][i4 * 4] = *(const float4*)&q[ql * NPIX + i0 + i4 * 4];
    }
    if (t < 64) { mls[t] = rm[i0 + t]; rls[t] = rl[i0 + t]; }

    const int igA = t & 15, jgA = t >> 4;
    const int cg  = t & 15, ig2 = t >> 4;

    float acc[4][4];
#pragma unroll
    for (int i = 0; i < 4; ++i)
#pragma unroll
        for (int j = 0; j < 4; ++j) acc[i][j] = 0.f;

    for (int j0 = 0; j0 < NPIX; j0 += 32) {
        __syncthreads();
        {
            int ql = t >> 3, j4 = t & 7;
            *(float4*)&Ks[ql][j4 * 4] = *(const float4*)&k[ql * NPIX + j0 + j4 * 4];
        }
        for (int idx = t; idx < 2048; idx += 256) {
            int cl = idx >> 5, jl = idx & 31;
            Vt[jl][cl] = v[(c0 + cl) * NPIX + j0 + jl];
        }
        __syncthreads();

        {
            float s[4][2];
#pragma unroll
            for (int a = 0; a < 4; ++a) { s[a][0] = 0.f; s[a][1] = 0.f; }
#pragma unroll
            for (int qq = 0; qq < 32; ++qq) {
                float4 qa = *(const float4*)&Qs[qq][igA * 4];
                float2 kb = *(const float2*)&Ks[qq][jgA * 2];
                float qv[4] = {qa.x, qa.y, qa.z, qa.w};
#pragma unroll
                for (int a = 0; a < 4; ++a) {
                    s[a][0] = fmaf(qv[a], kb.x, s[a][0]);
                    s[a][1] = fmaf(qv[a], kb.y, s[a][1]);
                }
            }
#pragma unroll
            for (int jj = 0; jj < 2; ++jj) {
                float4 p = make_float4(
                    __expf(s[0][jj] - mls[igA * 4 + 0]) * rls[igA * 4 + 0],
                    __expf(s[1][jj] - mls[igA * 4 + 1]) * rls[igA * 4 + 1],
                    __expf(s[2][jj] - mls[igA * 4 + 2]) * rls[igA * 4 + 2],
                    __expf(s[3][jj] - mls[igA * 4 + 3]) * rls[igA * 4 + 3]);
                *(float4*)&Pt[jgA * 2 + jj][igA * 4] = p;
            }
        }
        __syncthreads();

#pragma unroll
        for (int jl = 0; jl < 32; ++jl) {
            float4 vv = *(const float4*)&Vt[jl][cg * 4];
            float4 pp = *(const float4*)&Pt[jl][ig2 * 4];
            float va[4] = {vv.x, vv.y, vv.z, vv.w};
            float pa[4] = {pp.x, pp.y, pp.z, pp.w};
#pragma unroll
            for (int cc = 0; cc < 4; ++cc)
#pragma unroll
                for (int ii = 0; ii < 4; ++ii)
                    acc[cc][ii] = fmaf(va[cc], pa[ii], acc[cc][ii]);
        }
    }

    float gamma = gp[0];
#pragma unroll
    for (int cc = 0; cc < 4; ++cc) {
        int c = c0 + cg * 4 + cc;
        const float4 cvx = *(const float4*)&cv[c * NPIX + i0 + ig2 * 4];
        float4 zo = make_float4(gamma * acc[cc][0] + cvx.x,
                                gamma * acc[cc][1] + cvx.y,
                                gamma * acc[cc][2] + cvx.z,
                                gamma * acc[cc][3] + cvx.w);
        *(float4*)&z[c * NPIX + i0 + ig2 * 4] = zo;
    }
}

// ---------------------------------------------------------------------------
// Host launcher
// ---------------------------------------------------------------------------
// ws layout (float slots):
//   conv [4modb][256][4096]   @ 0          (4,194,304)
//   q    [2mod][2b][32][4096] @ 4,194,304  (524,288)
//   k                          @ 4,718,592 (524,288)
//   v    [2mod][2b][256][4096]@ 5,242,880  (4,194,304)
//   z                          @ 9,437,184 (4,194,304)
//   rowm [2o][2b][4096]       @ 13,631,488 (16,384)
//   rowl                       @ 13,647,872 (16,384)
//   scA  [2][256]             @ 13,664,256 (512)
//   shB  [2][256]             @ 13,664,768 (512)
//   zrow (512 bf16)           @ 13,665,280 (256)
//   Wt   bf16 [2][9][256][512]@ 13,665,536 (1,179,648)
//   Xp   bf16 [4][4096][512]  @ 14,845,184 (4,194,304)
//   total 19,039,488 floats = 76.2 MiB
extern "C" void kernel_launch(void* const* d_in, const int* in_sizes, int n_in,
                              void* d_out, int out_size, void* d_ws, size_t ws_size,
                              hipStream_t stream)
{
    const float* in_rgb = (const float*)d_in[0];
    const float* in_dsm = (const float*)d_in[1];
    auto P = [&](int i) { return (const float*)d_in[i]; };

    float* ws   = (float*)d_ws;
    float* conv = ws;
    float* qb_  = ws + 4194304;
    float* kb_  = ws + 4718592;
    float* vb_  = ws + 5242880;
    float* zb_  = ws + 9437184;
    float* rmb  = ws + 13631488;
    float* rlb  = ws + 13647872;
    float* scA  = ws + 13664256;
    float* shB  = ws + 13664768;
    __bf16* zrow = (__bf16*)(ws + 13665280);
    __bf16* Wt   = (__bf16*)(ws + 13665536);
    __bf16* Xp   = (__bf16*)(ws + 14845184);
    const long MODC = 2097152;
    const long MODQ = 262144;

    // prep: weight transpose + BN tables + zero row; X transpose to [pix][ic] bf16
    prep_w<<<2307, 256, 0, stream>>>(
        P(2), P(18), P(3), P(4), P(5), P(6), P(7),
        P(19), P(20), P(21), P(22), P(23),
        Wt, scA, shB, zrow);
    xpose<<<dim3(128, 16, 4), 256, 0, stream>>>(in_rgb, in_dsm, Xp);

    // conv3x3 + BN + PReLU as one MFMA dispatch (all mod/batch in grid.z)
    conv_mfma<<<dim3(32, 2, 4), 256, 0, stream>>>(
        Wt, Xp, zrow, scA, shB, P(8), P(24), conv);

    // q, k, v projections
    for (int mod = 0; mod < 2; ++mod) {
        int base = mod ? 18 : 2;
        gemm1x1<<<dim3(32, 1, 2), 256, 0, stream>>>(
            P(base + 7), conv + mod * MODC, 1048576, P(base + 8),
            qb_ + mod * MODQ, 131072, nullptr, 0, nullptr, 0, 32, 0);
        gemm1x1<<<dim3(32, 1, 2), 256, 0, stream>>>(
            P(base + 9), conv + mod * MODC, 1048576, P(base + 10),
            kb_ + mod * MODQ, 131072, nullptr, 0, nullptr, 0, 32, 0);
        gemm1x1<<<dim3(32, 8, 2), 256, 0, stream>>>(
            P(base + 11), conv + mod * MODC, 1048576, P(base + 12),
            vb_ + mod * MODC, 1048576, nullptr, 0, nullptr, 0, 256, 0);
    }
    // attention row stats: output modality o uses Q from other(o), K from o
    for (int o = 0; o < 2; ++o) {
        int other = 1 - o;
        attn_stats<<<dim3(64, 2), 256, 0, stream>>>(
            qb_ + other * MODQ, kb_ + o * MODQ, rmb + o * 8192, rlb + o * 8192);
    }
    // PV + gamma-gate + conv residual -> z
    for (int o = 0; o < 2; ++o) {
        int other = 1 - o;
        int base = o ? 18 : 2;
        attn_pv<<<dim3(64, 4, 2), 256, 0, stream>>>(
            qb_ + other * MODQ, kb_ + o * MODQ, vb_ + o * MODC, conv + o * MODC,
            zb_ + o * MODC, rmb + o * 8192, rlb + o * 8192, P(base + 15));
    }
    // up projection + input residual -> fp32 out
    for (int o = 0; o < 2; ++o) {
        int base = o ? 18 : 2;
        const float* xin = o ? in_dsm : in_rgb;
        gemm1x1<<<dim3(32, 16, 2), 256, 0, stream>>>(
            P(base + 13), zb_ + o * MODC, 1048576, P(base + 14),
            nullptr, 0, xin, 2097152, (float*)d_out + (long)o * 4194304, 2097152,
            512, 1);
    }
}

// Round 5
// 631.389 us; speedup vs baseline: 4.1562x; 2.6172x over previous
//
#include <hip/hip_runtime.h>
#include <hip/hip_bf16.h>
#include <stdint.h>

// fp32 I/O. Conv3x3 + attention (stats S, PV) run as bf16 MFMA.
// CRITICAL: softmax stats (m,l) and P must come from the SAME bf16 MFMA S
// (unscaled attention -> near-argmax softmax; any S mismatch scales o by exp(dS)).

constexpr int CINCH = 512;
constexpr int CDCH  = 256;
constexpr int CQCH  = 32;
constexpr int IMG   = 64;
constexpr int NPIX  = 4096;   // 64*64

typedef __bf16 bf16x8 __attribute__((ext_vector_type(8)));
typedef __bf16 bf16x4 __attribute__((ext_vector_type(4)));
typedef float  f32x4  __attribute__((ext_vector_type(4)));

__device__ __forceinline__ __bf16 f2b(float f) {
    __hip_bfloat16 h = __float2bfloat16(f);
    return *reinterpret_cast<__bf16*>(&h);
}

__device__ __forceinline__ void load_lds16(const void* g, void* l) {
    __builtin_amdgcn_global_load_lds(
        (const __attribute__((address_space(1))) unsigned int*)(uintptr_t)g,
        (__attribute__((address_space(3))) unsigned int*)(uintptr_t)l,
        16, 0, 0);
}

// ---------------------------------------------------------------------------
// Prep A: weights fp32 [oc][ic][9] -> Wt bf16 [mod][tap][oc][ic]; BN tables;
// zero row. grid 2307 x 256.
// ---------------------------------------------------------------------------
__global__ __launch_bounds__(256)
void prep_w(const float* __restrict__ w_r, const float* __restrict__ w_d,
            const float* __restrict__ cb_r, const float* __restrict__ bg_r,
            const float* __restrict__ bb_r, const float* __restrict__ bm_r,
            const float* __restrict__ bv_r,
            const float* __restrict__ cb_d, const float* __restrict__ bg_d,
            const float* __restrict__ bb_d, const float* __restrict__ bm_d,
            const float* __restrict__ bv_d,
            __bf16* __restrict__ Wt, float* __restrict__ scA,
            float* __restrict__ shB, __bf16* __restrict__ zrow)
{
    const int t = threadIdx.x;
    const int blk = blockIdx.x;
    if (blk < 2304) {
        int gid = blk * 1024 + t * 4;
        int mod = gid >= 1179648;
        int o2  = gid - mod * 1179648;
        int tap = o2 >> 17;
        int r   = o2 & 131071;
        int oc  = r >> 9;
        int ic  = r & 511;
        const float* wsrc = mod ? w_d : w_r;
        long base = ((long)(oc * 512 + ic)) * 9 + tap;
        bf16x4 v;
        v.x = f2b(wsrc[base]);
        v.y = f2b(wsrc[base + 9]);
        v.z = f2b(wsrc[base + 18]);
        v.w = f2b(wsrc[base + 27]);
        *(bf16x4*)&Wt[gid] = v;
    } else if (blk == 2304) {
        unsigned short* z = (unsigned short*)zrow;
        z[t] = 0; z[t + 256] = 0;
    } else {
        int mod = blk - 2305;
        const float* cb = mod ? cb_d : cb_r;
        const float* bg = mod ? bg_d : bg_r;
        const float* bb = mod ? bb_d : bb_r;
        const float* bm = mod ? bm_d : bm_r;
        const float* bv = mod ? bv_d : bv_r;
        int oc = t;
        float sc = bg[oc] * rsqrtf(bv[oc] + 1e-5f);
        scA[mod * 256 + oc] = sc;
        shB[mod * 256 + oc] = (cb[oc] - bm[oc]) * sc + bb[oc];
    }
}

// ---------------------------------------------------------------------------
// Prep B: X fp32 [mod][b][512][4096] -> Xp bf16 [modb][4096pix][512ic]
// ---------------------------------------------------------------------------
__global__ __launch_bounds__(256)
void xpose(const float* __restrict__ inr, const float* __restrict__ ind,
           __bf16* __restrict__ Xp)
{
    __shared__ float tile[32][33];
    const int t = threadIdx.x;
    const int p0 = blockIdx.x * 32;
    const int ic0 = blockIdx.y * 32;
    const int mb = blockIdx.z;
    const int mod = mb >> 1, b = mb & 1;
    const float* src = (mod ? ind : inr) + (long)b * CINCH * NPIX;

    int i = t >> 3, j4 = (t & 7) * 4;
    float4 v = *(const float4*)&src[(long)(ic0 + i) * NPIX + p0 + j4];
    tile[i][j4 + 0] = v.x; tile[i][j4 + 1] = v.y;
    tile[i][j4 + 2] = v.z; tile[i][j4 + 3] = v.w;
    __syncthreads();
    int j = t >> 3, i4 = (t & 7) * 4;
    bf16x4 o;
    o.x = f2b(tile[i4 + 0][j]);
    o.y = f2b(tile[i4 + 1][j]);
    o.z = f2b(tile[i4 + 2][j]);
    o.w = f2b(tile[i4 + 3][j]);
    *(bf16x4*)&Xp[((long)mb * NPIX + p0 + j) * 512 + ic0 + i4] = o;
}

// ---------------------------------------------------------------------------
// Conv3x3 implicit-GEMM MFMA (verified round 3).
// ---------------------------------------------------------------------------
__global__ __launch_bounds__(256)
void conv_mfma(const __bf16* __restrict__ Wt, const __bf16* __restrict__ Xp,
               const __bf16* __restrict__ zrow, const float* __restrict__ scA,
               const float* __restrict__ shB, const float* __restrict__ prr,
               const float* __restrict__ prd, float* __restrict__ conv)
{
    __shared__ __bf16 As[128 * 32];
    __shared__ __bf16 Bs[128 * 32];

    const int t = threadIdx.x;
    const int n0 = blockIdx.x * 128;
    const int m0 = blockIdx.y * 128;
    const int mb = blockIdx.z;
    const int mod = mb >> 1;

    const __bf16* Am = Wt + (long)mod * 9 * 256 * 512;
    const __bf16* Xb = Xp + (long)mb * NPIX * 512;

    const int rowa = t >> 2;
    const int c16  = t & 3;
    char* ldsA0 = (char*)As + (t >> 6) * 1024;
    char* ldsA1 = ldsA0 + 4096;
    char* ldsB0 = (char*)Bs + (t >> 6) * 1024;
    char* ldsB1 = ldsB0 + 4096;

    const int lane = t & 63;
    const int quad = lane >> 4;
    const int l15  = lane & 15;
    const int w    = t >> 6;
    const int mw0  = (w >> 1) * 64;
    const int nw0  = (w & 1) * 64;
    const char* abase = (const char*)As + (mw0 + l15) * 64 + quad * 16;
    const char* bbase = (const char*)Bs + (nw0 + l15) * 64 + quad * 16;

    f32x4 acc[4][4];
#pragma unroll
    for (int i = 0; i < 4; ++i)
#pragma unroll
        for (int j = 0; j < 4; ++j) acc[i][j] = (f32x4)0.f;

    for (int tap = 0; tap < 9; ++tap) {
        const int dy = tap / 3 - 1, dx = tap % 3 - 1;
        const __bf16* srcA = Am + (long)tap * 131072 + (long)(m0 + rowa) * 512 + c16 * 8;
        const __bf16* srcB0; const __bf16* srcB1;
        bool v0, v1;
        {
            int n = n0 + rowa;
            int x = n & 63, y = n >> 6;
            v0 = !((dx == -1 && x == 0) || (dx == 1 && x == 63) ||
                   (dy == -1 && y == 0) || (dy == 1 && y == 63));
            srcB0 = v0 ? (Xb + (long)(n + dy * 64 + dx) * 512 + c16 * 8)
                       : (zrow + c16 * 8);
            n += 64; x = n & 63; y = n >> 6;
            v1 = !((dx == -1 && x == 0) || (dx == 1 && x == 63) ||
                   (dy == -1 && y == 0) || (dy == 1 && y == 63));
            srcB1 = v1 ? (Xb + (long)(n + dy * 64 + dx) * 512 + c16 * 8)
                       : (zrow + c16 * 8);
        }

        for (int ic0 = 0; ic0 < 512; ic0 += 32) {
            load_lds16(srcA + ic0, ldsA0);
            load_lds16(srcA + ic0 + 32768, ldsA1);
            load_lds16(srcB0 + (v0 ? ic0 : 0), ldsB0);
            load_lds16(srcB1 + (v1 ? ic0 : 0), ldsB1);
            __syncthreads();

            bf16x8 af[4], bfr[4];
#pragma unroll
            for (int i = 0; i < 4; ++i) af[i]  = *(const bf16x8*)(abase + i * 1024);
#pragma unroll
            for (int j = 0; j < 4; ++j) bfr[j] = *(const bf16x8*)(bbase + j * 1024);
#pragma unroll
            for (int i = 0; i < 4; ++i)
#pragma unroll
                for (int j = 0; j < 4; ++j)
                    acc[i][j] = __builtin_amdgcn_mfma_f32_16x16x32_bf16(
                        af[i], bfr[j], acc[i][j], 0, 0, 0);
            __syncthreads();
        }
    }

    const float alpha = (mod ? prd : prr)[0];
    float* outp = conv + (long)mb * 256 * NPIX;
#pragma unroll
    for (int i = 0; i < 4; ++i) {
#pragma unroll
        for (int r = 0; r < 4; ++r) {
            int oc = m0 + mw0 + 16 * i + quad * 4 + r;
            float sc = scA[mod * 256 + oc];
            float sh = shB[mod * 256 + oc];
            float* orow = outp + (long)oc * NPIX;
#pragma unroll
            for (int j = 0; j < 4; ++j) {
                int n = n0 + nw0 + 16 * j + l15;
                float y = acc[i][j][r] * sc + sh;
                y = (y > 0.f) ? y : alpha * y;
                orow[n] = y;
            }
        }
    }
}

// ---------------------------------------------------------------------------
// 1x1 conv GEMM (fp32 vector).
// ---------------------------------------------------------------------------
__global__ __launch_bounds__(256)
void gemm1x1(const float* __restrict__ A, const float* __restrict__ Bbase, long strideB,
             const float* __restrict__ bias,
             float* __restrict__ Cbase, long strideC,
             const float* __restrict__ residBase, long strideR,
             float* __restrict__ obase, long strideO,
             int M, int mode)
{
    __shared__ float As[32][36];
    __shared__ float Bs[32][128];

    const int t  = threadIdx.x;
    const int n0 = blockIdx.x * 128;
    const int m0 = blockIdx.y * 32;
    const int b  = blockIdx.z;
    const float* Bm = Bbase + b * strideB;
    const int tm = t >> 5, tn = t & 31;

    float acc[4][4];
#pragma unroll
    for (int i = 0; i < 4; ++i)
#pragma unroll
        for (int j = 0; j < 4; ++j) acc[i][j] = 0.f;

    for (int kc = 0; kc < 256; kc += 32) {
        {
            int ml = t >> 3, kq = t & 7;
            float4 a4 = *(const float4*)&A[(m0 + ml) * 256 + kc + kq * 4];
            As[kq * 4 + 0][ml] = a4.x;
            As[kq * 4 + 1][ml] = a4.y;
            As[kq * 4 + 2][ml] = a4.z;
            As[kq * 4 + 3][ml] = a4.w;
        }
        for (int idx = t; idx < 1024; idx += 256) {
            int kl = idx >> 5, n4 = idx & 31;
            *(float4*)&Bs[kl][n4 * 4] = *(const float4*)&Bm[(kc + kl) * NPIX + n0 + n4 * 4];
        }
        __syncthreads();

#pragma unroll
        for (int kk = 0; kk < 32; ++kk) {
            float4 a4 = *(const float4*)&As[kk][tm * 4];
            float4 b4 = *(const float4*)&Bs[kk][tn * 4];
            float av[4] = {a4.x, a4.y, a4.z, a4.w};
            float bw[4] = {b4.x, b4.y, b4.z, b4.w};
#pragma unroll
            for (int i = 0; i < 4; ++i)
#pragma unroll
                for (int j = 0; j < 4; ++j) acc[i][j] = fmaf(av[i], bw[j], acc[i][j]);
        }
        __syncthreads();
    }

    if (mode == 0) {
        float* C = Cbase + b * strideC;
#pragma unroll
        for (int i = 0; i < 4; ++i) {
            int m = m0 + tm * 4 + i;
            float bi = bias[m];
            float4 o4 = make_float4(acc[i][0] + bi, acc[i][1] + bi,
                                    acc[i][2] + bi, acc[i][3] + bi);
            *(float4*)&C[(long)m * NPIX + n0 + tn * 4] = o4;
        }
    } else {
        const float* R = residBase + b * strideR;
        float* O = obase + b * strideO;
#pragma unroll
        for (int i = 0; i < 4; ++i) {
            int m = m0 + tm * 4 + i;
            float bi = bias[m];
            long off = (long)m * NPIX + n0 + tn * 4;
            float4 r4 = *(const float4*)&R[off];
            float4 o4 = make_float4(acc[i][0] + bi + r4.x, acc[i][1] + bi + r4.y,
                                    acc[i][2] + bi + r4.z, acc[i][3] + bi + r4.w);
            *(float4*)&O[off] = o4;
        }
    }
}

// ---------------------------------------------------------------------------
// q/k fp32 [32][4096] -> bf16 transposed [4096][32]. grid (128, 8).
// ---------------------------------------------------------------------------
__global__ __launch_bounds__(256)
void qk_t(const float* __restrict__ qb, const float* __restrict__ kb,
          __bf16* __restrict__ Qt, __bf16* __restrict__ Kt)
{
    __shared__ float tile[32][33];
    const int t = threadIdx.x;
    const int p0 = blockIdx.x * 32;
    const int y = blockIdx.y;
    const int mb = y & 3;
    const float* src = ((y & 4) ? kb : qb) + (long)mb * 131072;
    __bf16* dst = ((y & 4) ? Kt : Qt) + (long)mb * 131072;

    int qr = t >> 3, p4 = (t & 7) * 4;
    float4 v = *(const float4*)&src[qr * 4096 + p0 + p4];
    tile[qr][p4 + 0] = v.x; tile[qr][p4 + 1] = v.y;
    tile[qr][p4 + 2] = v.z; tile[qr][p4 + 3] = v.w;
    __syncthreads();
    int pl = t >> 3, q4 = (t & 7) * 4;
    bf16x4 o;
    o.x = f2b(tile[q4 + 0][pl]); o.y = f2b(tile[q4 + 1][pl]);
    o.z = f2b(tile[q4 + 2][pl]); o.w = f2b(tile[q4 + 3][pl]);
    *(bf16x4*)&dst[(p0 + pl) * 32 + q4] = o;
}

// ---------------------------------------------------------------------------
// V fp32 -> bf16 elementwise. grid 4096 x 256.
// ---------------------------------------------------------------------------
__global__ __launch_bounds__(256)
void vcast(const float* __restrict__ v, __bf16* __restrict__ Vb)
{
    long idx = ((long)blockIdx.x * 256 + threadIdx.x) * 4;
    float4 f = *(const float4*)&v[idx];
    bf16x4 o; o.x = f2b(f.x); o.y = f2b(f.y); o.z = f2b(f.z); o.w = f2b(f.w);
    *(bf16x4*)&Vb[idx] = o;
}

// ---------------------------------------------------------------------------
// MFMA row stats: S via the SAME bf16 MFMA as attn_pv_mfma (bit-identical),
// two passes (max, sum-exp). Block: 128 i rows x all 4096 j.
// grid (32 i-tiles, 4 = o*2+b).
// ---------------------------------------------------------------------------
__global__ __launch_bounds__(256)
void attn_stats_mfma(const __bf16* __restrict__ Qt, const __bf16* __restrict__ Kt,
                     float* __restrict__ rmb, float* __restrict__ rlb)
{
    __shared__ __bf16 Qs[128 * 32];   // [i][32q]  8KB
    __shared__ __bf16 Ks[128 * 32];   // [j][32q]  8KB
    __shared__ float red[2][128];
    __shared__ float mfin[128];

    const int t  = threadIdx.x;
    const int i0 = blockIdx.x * 128;
    const int o  = blockIdx.y >> 1, b = blockIdx.y & 1;
    const int mbK = o * 2 + b, mbQ = (1 - o) * 2 + b;

    const __bf16* Qg = Qt + (long)mbQ * 131072;
    const __bf16* Kg = Kt + (long)mbK * 131072;

    const int lane = t & 63, quad = lane >> 4, l15 = lane & 15, w = t >> 6;
    const int mS = (w >> 1) * 64;   // i-half of wave
    const int nS = (w & 1) * 64;    // j-half within 128-chunk

    load_lds16((const char*)Qg + (long)i0 * 64 + t * 16, (char*)Qs + (t >> 6) * 1024);
    load_lds16((const char*)Qg + (long)i0 * 64 + 4096 + t * 16,
               (char*)Qs + 4096 + (t >> 6) * 1024);
    __syncthreads();

    bf16x8 qa[4];
#pragma unroll
    for (int fi = 0; fi < 4; ++fi)
        qa[fi] = *(const bf16x8*)((const char*)Qs + (mS + 16 * fi + l15) * 64 + quad * 16);

    const f32x4 zero4 = (f32x4)0.f;
    float mloc[16];
#pragma unroll
    for (int e = 0; e < 16; ++e) mloc[e] = -3.0e38f;

    // pass 1: row max
    for (int j0 = 0; j0 < 4096; j0 += 128) {
        __syncthreads();
        load_lds16((const char*)Kg + (long)j0 * 64 + t * 16, (char*)Ks + (t >> 6) * 1024);
        load_lds16((const char*)Kg + (long)j0 * 64 + 4096 + t * 16,
                   (char*)Ks + 4096 + (t >> 6) * 1024);
        __syncthreads();
#pragma unroll
        for (int fj = 0; fj < 4; ++fj) {
            bf16x8 kb = *(const bf16x8*)((const char*)Ks + (nS + 16 * fj + l15) * 64 + quad * 16);
#pragma unroll
            for (int fi = 0; fi < 4; ++fi) {
                f32x4 s = __builtin_amdgcn_mfma_f32_16x16x32_bf16(qa[fi], kb, zero4, 0, 0, 0);
#pragma unroll
                for (int r = 0; r < 4; ++r)
                    mloc[fi * 4 + r] = fmaxf(mloc[fi * 4 + r], s[r]);
            }
        }
    }
#pragma unroll
    for (int d = 1; d < 16; d <<= 1)
#pragma unroll
        for (int e = 0; e < 16; ++e)
            mloc[e] = fmaxf(mloc[e], __shfl_xor(mloc[e], d, 64));
    if (l15 == 0) {
#pragma unroll
        for (int fi = 0; fi < 4; ++fi)
#pragma unroll
            for (int r = 0; r < 4; ++r)
                red[w & 1][mS + 16 * fi + quad * 4 + r] = mloc[fi * 4 + r];
    }
    __syncthreads();
    if (t < 128) mfin[t] = fmaxf(red[0][t], red[1][t]);
    __syncthreads();

    float mi[16];
#pragma unroll
    for (int fi = 0; fi < 4; ++fi)
#pragma unroll
        for (int r = 0; r < 4; ++r)
            mi[fi * 4 + r] = mfin[mS + 16 * fi + quad * 4 + r];
    float sloc[16];
#pragma unroll
    for (int e = 0; e < 16; ++e) sloc[e] = 0.f;

    // pass 2: sum exp(S - m)
    for (int j0 = 0; j0 < 4096; j0 += 128) {
        __syncthreads();
        load_lds16((const char*)Kg + (long)j0 * 64 + t * 16, (char*)Ks + (t >> 6) * 1024);
        load_lds16((const char*)Kg + (long)j0 * 64 + 4096 + t * 16,
                   (char*)Ks + 4096 + (t >> 6) * 1024);
        __syncthreads();
#pragma unroll
        for (int fj = 0; fj < 4; ++fj) {
            bf16x8 kb = *(const bf16x8*)((const char*)Ks + (nS + 16 * fj + l15) * 64 + quad * 16);
#pragma unroll
            for (int fi = 0; fi < 4; ++fi) {
                f32x4 s = __builtin_amdgcn_mfma_f32_16x16x32_bf16(qa[fi], kb, zero4, 0, 0, 0);
#pragma unroll
                for (int r = 0; r < 4; ++r)
                    sloc[fi * 4 + r] += __expf(s[r] - mi[fi * 4 + r]);
            }
        }
    }
#pragma unroll
    for (int d = 1; d < 16; d <<= 1)
#pragma unroll
        for (int e = 0; e < 16; ++e)
            sloc[e] += __shfl_xor(sloc[e], d, 64);
    if (l15 == 0) {
#pragma unroll
        for (int fi = 0; fi < 4; ++fi)
#pragma unroll
            for (int r = 0; r < 4; ++r)
                red[w & 1][mS + 16 * fi + quad * 4 + r] = sloc[fi * 4 + r];
    }
    __syncthreads();
    if (t < 128) {
        float l = red[0][t] + red[1][t];
        rmb[o * 8192 + b * 4096 + i0 + t] = mfin[t];
        rlb[o * 8192 + b * 4096 + i0 + t] = 1.f / l;
    }
}

// ---------------------------------------------------------------------------
// Fused MFMA PV: S = Q^T K (MFMA, K=32) -> P = exp(S-m)*rl (bf16, LDS) ->
// acc += V P^T (MFMA over j). z = gamma*acc + conv (fp32).
// Block: 128c x 128i, j-chunks of 64. grid (32 i, 2 c, 4 = o*2+b).
// ---------------------------------------------------------------------------
__global__ __launch_bounds__(256)
void attn_pv_mfma(const __bf16* __restrict__ Qt, const __bf16* __restrict__ Kt,
                  const __bf16* __restrict__ Vb, const float* __restrict__ convb,
                  float* __restrict__ zb, const float* __restrict__ rmb,
                  const float* __restrict__ rlb, const float* __restrict__ g_r,
                  const float* __restrict__ g_d)
{
    __shared__ __bf16 Qs[128 * 32];     // [i][32q] 64B rows   (8KB)
    __shared__ __bf16 Ks[64 * 32];      // [j][32q]            (4KB)
    __shared__ __bf16 Vs[2 * 128 * 32]; // [ks][c][32j]        (16KB)
    __shared__ __bf16 Ps[2 * 128 * 32]; // [ks][i][32j]        (16KB)

    const int t  = threadIdx.x;
    const int i0 = blockIdx.x * 128;
    const int c0 = blockIdx.y * 128;
    const int o  = blockIdx.z >> 1, b = blockIdx.z & 1;
    const int mbK = o * 2 + b, mbQ = (1 - o) * 2 + b;

    const __bf16* Qg = Qt + (long)mbQ * 131072;
    const __bf16* Kg = Kt + (long)mbK * 131072;
    const __bf16* Vg = Vb + (long)mbK * 1048576;
    const float* cvg = convb + (long)mbK * 1048576;
    float* zg = zb + (long)mbK * 1048576;
    const float* rm = rmb + o * 8192 + b * 4096;
    const float* rl = rlb + o * 8192 + b * 4096;

    const int lane = t & 63, quad = lane >> 4, l15 = lane & 15, w = t >> 6;
    const int mw = (w >> 1) * 64;   // PV: c-range of wave
    const int nw = (w & 1) * 64;    // PV: i-range of wave
    const int mS = (w >> 1) * 64;   // S: i-range of wave
    const int nS = (w & 1) * 32;    // S: j-range of wave
    const int ksP = w & 1;          // Ps slab this wave writes

    // stage Q tile once (8KB = 2 issues)
    load_lds16((const char*)Qg + (long)i0 * 64 + t * 16, (char*)Qs + (t >> 6) * 1024);
    load_lds16((const char*)Qg + (long)i0 * 64 + 4096 + t * 16,
               (char*)Qs + 4096 + (t >> 6) * 1024);

    // preload per-lane softmax stats (rows of S this lane produces)
    float mlv[16], rlv[16];
#pragma unroll
    for (int fi = 0; fi < 4; ++fi)
#pragma unroll
        for (int r = 0; r < 4; ++r) {
            int i = i0 + mS + 16 * fi + quad * 4 + r;
            mlv[fi * 4 + r] = rm[i];
            rlv[fi * 4 + r] = rl[i];
        }

    f32x4 acc[4][4];
#pragma unroll
    for (int i = 0; i < 4; ++i)
#pragma unroll
        for (int j = 0; j < 4; ++j) acc[i][j] = (f32x4)0.f;
    const f32x4 zero4 = (f32x4)0.f;

    for (int j0 = 0; j0 < 4096; j0 += 64) {
        __syncthreads();   // previous chunk's reads done before overwrite
        // stage K chunk [64j][32q] (4KB = 1 issue)
        load_lds16((const char*)Kg + (long)j0 * 64 + t * 16, (char*)Ks + (t >> 6) * 1024);
        // stage V chunk [ks][128c][32j] (16KB = 4 issues)
#pragma unroll
        for (int ii = 0; ii < 4; ++ii) {
            int s = ii * 256 + t;
            int ks = s >> 9, cc = (s >> 2) & 127, blk = s & 3;
            load_lds16((const char*)Vg + (long)(c0 + cc) * 8192 + (j0 + ks * 32) * 2 + blk * 16,
                       (char*)Vs + ii * 4096 + (t >> 6) * 1024);
        }
        __syncthreads();   // staging visible

        // S-MFMA: per wave 64i x 32j, K=32
        bf16x8 qa[4], kb2[2];
#pragma unroll
        for (int fi = 0; fi < 4; ++fi)
            qa[fi] = *(const bf16x8*)((const char*)Qs + (mS + 16 * fi + l15) * 64 + quad * 16);
#pragma unroll
        for (int fj = 0; fj < 2; ++fj)
            kb2[fj] = *(const bf16x8*)((const char*)Ks + (nS + 16 * fj + l15) * 64 + quad * 16);
        f32x4 sA[4][2];
#pragma unroll
        for (int fi = 0; fi < 4; ++fi)
#pragma unroll
            for (int fj = 0; fj < 2; ++fj)
                sA[fi][fj] = __builtin_amdgcn_mfma_f32_16x16x32_bf16(
                    qa[fi], kb2[fj], zero4, 0, 0, 0);

        // P = exp(S - m) * rl -> Ps[ksP][i][32j]  (disjoint per wave)
        __bf16* prow = Ps + ksP * 4096;
#pragma unroll
        for (int fi = 0; fi < 4; ++fi)
#pragma unroll
            for (int fj = 0; fj < 2; ++fj) {
                int jl = 16 * fj + l15;
#pragma unroll
                for (int r = 0; r < 4; ++r) {
                    float p = __expf(sA[fi][fj][r] - mlv[fi * 4 + r]) * rlv[fi * 4 + r];
                    prow[(mS + 16 * fi + quad * 4 + r) * 32 + jl] = f2b(p);
                }
            }
        __syncthreads();   // Ps visible to all waves

        // PV-MFMA: per wave 64c x 64i, K=64 (2 slabs)
#pragma unroll
        for (int ks = 0; ks < 2; ++ks) {
            bf16x8 va[4], pb[4];
#pragma unroll
            for (int fi = 0; fi < 4; ++fi)
                va[fi] = *(const bf16x8*)((const char*)Vs + ks * 8192 +
                                          (mw + 16 * fi + l15) * 64 + quad * 16);
#pragma unroll
            for (int fj = 0; fj < 4; ++fj)
                pb[fj] = *(const bf16x8*)((const char*)Ps + ks * 8192 +
                                          (nw + 16 * fj + l15) * 64 + quad * 16);
#pragma unroll
            for (int fi = 0; fi < 4; ++fi)
#pragma unroll
                for (int fj = 0; fj < 4; ++fj)
                    acc[fi][fj] = __builtin_amdgcn_mfma_f32_16x16x32_bf16(
                        va[fi], pb[fj], acc[fi][fj], 0, 0, 0);
        }
    }

    // epilogue: z = gamma*acc + conv (fp32 store)
    const float gamma = (o ? g_d : g_r)[0];
#pragma unroll
    for (int fi = 0; fi < 4; ++fi) {
#pragma unroll
        for (int r = 0; r < 4; ++r) {
            int c = c0 + mw + 16 * fi + quad * 4 + r;
            const float* crow = cvg + (long)c * 4096;
            float* zr = zg + (long)c * 4096;
#pragma unroll
            for (int fj = 0; fj < 4; ++fj) {
                int i = i0 + nw + 16 * fj + l15;
                zr[i] = gamma * acc[fi][fj][r] + crow[i];
            }
        }
    }
}

// ---------------------------------------------------------------------------
// Host launcher
// ---------------------------------------------------------------------------
// ws layout (float slots):
//   conv [4modb][256][4096]   @ 0           (4,194,304)
//   q    [2mod][2b][32][4096] @ 4,194,304   (524,288)
//   k                          @ 4,718,592  (524,288)
//   v    [2mod][2b][256][4096]@ 5,242,880   (4,194,304)
//   z                          @ 9,437,184  (4,194,304)
//   rowm [2o][2b][4096]       @ 13,631,488  (16,384)
//   rowl                       @ 13,647,872 (16,384)
//   scA  [2][256]             @ 13,664,256  (512)
//   shB  [2][256]             @ 13,664,768  (512)
//   zrow (512 bf16)           @ 13,665,280  (256)
//   Wt   bf16 [2][9][256][512]@ 13,665,536  (1,179,648)
//   Xp   bf16 [4][4096][512]  @ 14,845,184  (4,194,304)
//   Qt   bf16 [4][4096][32]   @ 19,039,488  (262,144)
//   Kt   bf16 [4][4096][32]   @ 19,301,632  (262,144)
//   Vbb  bf16 [4][256][4096]  @ 19,563,776  (2,097,152)
//   total 21,660,928 floats = 86.6 MiB
extern "C" void kernel_launch(void* const* d_in, const int* in_sizes, int n_in,
                              void* d_out, int out_size, void* d_ws, size_t ws_size,
                              hipStream_t stream)
{
    const float* in_rgb = (const float*)d_in[0];
    const float* in_dsm = (const float*)d_in[1];
    auto P = [&](int i) { return (const float*)d_in[i]; };

    float* ws   = (float*)d_ws;
    float* conv = ws;
    float* qb_  = ws + 4194304;
    float* kb_  = ws + 4718592;
    float* vb_  = ws + 5242880;
    float* zb_  = ws + 9437184;
    float* rmb  = ws + 13631488;
    float* rlb  = ws + 13647872;
    float* scA  = ws + 13664256;
    float* shB  = ws + 13664768;
    __bf16* zrow = (__bf16*)(ws + 13665280);
    __bf16* Wt   = (__bf16*)(ws + 13665536);
    __bf16* Xp   = (__bf16*)(ws + 14845184);
    __bf16* Qt   = (__bf16*)(ws + 19039488);
    __bf16* Kt   = (__bf16*)(ws + 19301632);
    __bf16* Vbb  = (__bf16*)(ws + 19563776);
    const long MODC = 2097152;
    const long MODQ = 262144;

    prep_w<<<2307, 256, 0, stream>>>(
        P(2), P(18), P(3), P(4), P(5), P(6), P(7),
        P(19), P(20), P(21), P(22), P(23),
        Wt, scA, shB, zrow);
    xpose<<<dim3(128, 16, 4), 256, 0, stream>>>(in_rgb, in_dsm, Xp);

    conv_mfma<<<dim3(32, 2, 4), 256, 0, stream>>>(
        Wt, Xp, zrow, scA, shB, P(8), P(24), conv);

    // q, k, v projections (fp32)
    for (int mod = 0; mod < 2; ++mod) {
        int base = mod ? 18 : 2;
        gemm1x1<<<dim3(32, 1, 2), 256, 0, stream>>>(
            P(base + 7), conv + mod * MODC, 1048576, P(base + 8),
            qb_ + mod * MODQ, 131072, nullptr, 0, nullptr, 0, 32, 0);
        gemm1x1<<<dim3(32, 1, 2), 256, 0, stream>>>(
            P(base + 9), conv + mod * MODC, 1048576, P(base + 10),
            kb_ + mod * MODQ, 131072, nullptr, 0, nullptr, 0, 32, 0);
        gemm1x1<<<dim3(32, 8, 2), 256, 0, stream>>>(
            P(base + 11), conv + mod * MODC, 1048576, P(base + 12),
            vb_ + mod * MODC, 1048576, nullptr, 0, nullptr, 0, 256, 0);
    }
    // bf16 conversions for the MFMA attention
    qk_t<<<dim3(128, 8), 256, 0, stream>>>(qb_, kb_, Qt, Kt);
    vcast<<<4096, 256, 0, stream>>>(vb_, Vbb);

    // MFMA row stats (bit-identical S path to attn_pv_mfma)
    attn_stats_mfma<<<dim3(32, 4), 256, 0, stream>>>(Qt, Kt, rmb, rlb);

    // fused MFMA PV + gamma-gate + conv residual -> z (both o, both b)
    attn_pv_mfma<<<dim3(32, 2, 4), 256, 0, stream>>>(
        Qt, Kt, Vbb, conv, zb_, rmb, rlb, P(17), P(33));

    // up projection + input residual -> fp32 out
    for (int o = 0; o < 2; ++o) {
        int base = o ? 18 : 2;
        const float* xin = o ? in_dsm : in_rgb;
        gemm1x1<<<dim3(32, 16, 2), 256, 0, stream>>>(
            P(base + 13), zb_ + o * MODC, 1048576, P(base + 14),
            nullptr, 0, xin, 2097152, (float*)d_out + (long)o * 4194304, 2097152,
            512, 1);
    }
}

// Round 6
// 476.766 us; speedup vs baseline: 5.5041x; 1.3243x over previous
//
#include <hip/hip_runtime.h>
#include <hip/hip_bf16.h>
#include <stdint.h>

// fp32 I/O. Conv3x3, all 1x1 projections, and attention run as bf16 MFMA.
// CRITICAL: softmax stats (m,l) and P come from the SAME bf16 MFMA S path
// (unscaled attention -> near-argmax softmax; any S mismatch scales o by exp(dS)).

constexpr int CINCH = 512;
constexpr int NPIX  = 4096;   // 64*64

typedef __bf16 bf16x8 __attribute__((ext_vector_type(8)));
typedef __bf16 bf16x4 __attribute__((ext_vector_type(4)));
typedef float  f32x4  __attribute__((ext_vector_type(4)));

__device__ __forceinline__ __bf16 f2b(float f) {
    __hip_bfloat16 h = __float2bfloat16(f);
    return *reinterpret_cast<__bf16*>(&h);
}

__device__ __forceinline__ void load_lds16(const void* g, void* l) {
    __builtin_amdgcn_global_load_lds(
        (const __attribute__((address_space(1))) unsigned int*)(uintptr_t)g,
        (__attribute__((address_space(3))) unsigned int*)(uintptr_t)l,
        16, 0, 0);
}

// ---------------------------------------------------------------------------
// Prep A: conv weights fp32 [oc][ic][9] -> Wt bf16 [mod][tap][oc][ic];
// BN scale/shift tables; zero row. grid 2307 x 256.
// ---------------------------------------------------------------------------
__global__ __launch_bounds__(256)
void prep_w(const float* __restrict__ w_r, const float* __restrict__ w_d,
            const float* __restrict__ cb_r, const float* __restrict__ bg_r,
            const float* __restrict__ bb_r, const float* __restrict__ bm_r,
            const float* __restrict__ bv_r,
            const float* __restrict__ cb_d, const float* __restrict__ bg_d,
            const float* __restrict__ bb_d, const float* __restrict__ bm_d,
            const float* __restrict__ bv_d,
            __bf16* __restrict__ Wt, float* __restrict__ scA,
            float* __restrict__ shB, __bf16* __restrict__ zrow)
{
    const int t = threadIdx.x;
    const int blk = blockIdx.x;
    if (blk < 2304) {
        int gid = blk * 1024 + t * 4;
        int mod = gid >= 1179648;
        int o2  = gid - mod * 1179648;
        int tap = o2 >> 17;
        int r   = o2 & 131071;
        int oc  = r >> 9;
        int ic  = r & 511;
        const float* wsrc = mod ? w_d : w_r;
        long base = ((long)(oc * 512 + ic)) * 9 + tap;
        bf16x4 v;
        v.x = f2b(wsrc[base]);
        v.y = f2b(wsrc[base + 9]);
        v.z = f2b(wsrc[base + 18]);
        v.w = f2b(wsrc[base + 27]);
        *(bf16x4*)&Wt[gid] = v;
    } else if (blk == 2304) {
        unsigned short* z = (unsigned short*)zrow;
        z[t] = 0; z[t + 256] = 0;
    } else {
        int mod = blk - 2305;
        const float* cb = mod ? cb_d : cb_r;
        const float* bg = mod ? bg_d : bg_r;
        const float* bb = mod ? bb_d : bb_r;
        const float* bm = mod ? bm_d : bm_r;
        const float* bv = mod ? bv_d : bv_r;
        int oc = t;
        float sc = bg[oc] * rsqrtf(bv[oc] + 1e-5f);
        scA[mod * 256 + oc] = sc;
        shB[mod * 256 + oc] = (cb[oc] - bm[oc]) * sc + bb[oc];
    }
}

// ---------------------------------------------------------------------------
// Prep B: projection weights fp32 -> bf16. Wq/Wk padded to 128 rows (zeros).
// Layout per buffer: [2mod][rows][256]. grid 512 x 256 (4 elems/thread).
// ---------------------------------------------------------------------------
__global__ __launch_bounds__(256)
void prep_gw(const float* __restrict__ qw_r, const float* __restrict__ qw_d,
             const float* __restrict__ kw_r, const float* __restrict__ kw_d,
             const float* __restrict__ vw_r, const float* __restrict__ vw_d,
             const float* __restrict__ uw_r, const float* __restrict__ uw_d,
             __bf16* __restrict__ Wq, __bf16* __restrict__ Wk,
             __bf16* __restrict__ Wv, __bf16* __restrict__ Wu)
{
    int gid = blockIdx.x * 1024 + threadIdx.x * 4;
    __bf16* dst;
    float4 f = make_float4(0.f, 0.f, 0.f, 0.f);
    if (gid < 65536) {                       // Wq [2][128][256], valid rows < 32
        int mod = gid >> 15, e = gid & 32767;
        dst = Wq + gid;
        if (e < 8192) f = *(const float4*)((mod ? qw_d : qw_r) + e);
    } else if (gid < 131072) {               // Wk [2][128][256]
        int g = gid - 65536;
        int mod = g >> 15, e = g & 32767;
        dst = Wk + g;
        if (e < 8192) f = *(const float4*)((mod ? kw_d : kw_r) + e);
    } else if (gid < 262144) {               // Wv [2][256][256]
        int g = gid - 131072;
        int mod = g >> 16, e = g & 65535;
        dst = Wv + g;
        f = *(const float4*)((mod ? vw_d : vw_r) + e);
    } else {                                 // Wu [2][512][256]
        int g = gid - 262144;
        int mod = g >> 17, e = g & 131071;
        dst = Wu + g;
        f = *(const float4*)((mod ? uw_d : uw_r) + e);
    }
    bf16x4 o; o.x = f2b(f.x); o.y = f2b(f.y); o.z = f2b(f.z); o.w = f2b(f.w);
    *(bf16x4*)dst = o;
}

// ---------------------------------------------------------------------------
// Prep C: X fp32 [mod][b][512][4096] -> Xp bf16 [modb][4096pix][512ic]
// ---------------------------------------------------------------------------
__global__ __launch_bounds__(256)
void xpose(const float* __restrict__ inr, const float* __restrict__ ind,
           __bf16* __restrict__ Xp)
{
    __shared__ float tile[32][33];
    const int t = threadIdx.x;
    const int p0 = blockIdx.x * 32;
    const int ic0 = blockIdx.y * 32;
    const int mb = blockIdx.z;
    const int mod = mb >> 1, b = mb & 1;
    const float* src = (mod ? ind : inr) + (long)b * CINCH * NPIX;

    int i = t >> 3, j4 = (t & 7) * 4;
    float4 v = *(const float4*)&src[(long)(ic0 + i) * NPIX + p0 + j4];
    tile[i][j4 + 0] = v.x; tile[i][j4 + 1] = v.y;
    tile[i][j4 + 2] = v.z; tile[i][j4 + 3] = v.w;
    __syncthreads();
    int j = t >> 3, i4 = (t & 7) * 4;
    bf16x4 o;
    o.x = f2b(tile[i4 + 0][j]);
    o.y = f2b(tile[i4 + 1][j]);
    o.z = f2b(tile[i4 + 2][j]);
    o.w = f2b(tile[i4 + 3][j]);
    *(bf16x4*)&Xp[((long)mb * NPIX + p0 + j) * 512 + ic0 + i4] = o;
}

// ---------------------------------------------------------------------------
// Generic fp32 [mb][256][4096] -> bf16 transposed [mb][4096][256].
// grid (128, 8, 4).
// ---------------------------------------------------------------------------
__global__ __launch_bounds__(256)
void t256(const float* __restrict__ src, __bf16* __restrict__ dst)
{
    __shared__ float tile[32][33];
    const int t = threadIdx.x;
    const int p0 = blockIdx.x * 32;
    const int c0 = blockIdx.y * 32;
    const int mb = blockIdx.z;
    const float* s = src + (long)mb * 256 * NPIX;
    __bf16* d = dst + (long)mb * NPIX * 256;

    int i = t >> 3, j4 = (t & 7) * 4;
    float4 v = *(const float4*)&s[(long)(c0 + i) * NPIX + p0 + j4];
    tile[i][j4 + 0] = v.x; tile[i][j4 + 1] = v.y;
    tile[i][j4 + 2] = v.z; tile[i][j4 + 3] = v.w;
    __syncthreads();
    int j = t >> 3, i4 = (t & 7) * 4;
    bf16x4 o;
    o.x = f2b(tile[i4 + 0][j]); o.y = f2b(tile[i4 + 1][j]);
    o.z = f2b(tile[i4 + 2][j]); o.w = f2b(tile[i4 + 3][j]);
    *(bf16x4*)&d[((long)(p0 + j)) * 256 + c0 + i4] = o;
}

// ---------------------------------------------------------------------------
// Conv3x3 implicit-GEMM MFMA (verified round 3).
// ---------------------------------------------------------------------------
__global__ __launch_bounds__(256)
void conv_mfma(const __bf16* __restrict__ Wt, const __bf16* __restrict__ Xp,
               const __bf16* __restrict__ zrow, const float* __restrict__ scA,
               const float* __restrict__ shB, const float* __restrict__ prr,
               const float* __restrict__ prd, float* __restrict__ conv)
{
    __shared__ __bf16 As[128 * 32];
    __shared__ __bf16 Bs[128 * 32];

    const int t = threadIdx.x;
    const int n0 = blockIdx.x * 128;
    const int m0 = blockIdx.y * 128;
    const int mb = blockIdx.z;
    const int mod = mb >> 1;

    const __bf16* Am = Wt + (long)mod * 9 * 256 * 512;
    const __bf16* Xb = Xp + (long)mb * NPIX * 512;

    const int rowa = t >> 2;
    const int c16  = t & 3;
    char* ldsA0 = (char*)As + (t >> 6) * 1024;
    char* ldsA1 = ldsA0 + 4096;
    char* ldsB0 = (char*)Bs + (t >> 6) * 1024;
    char* ldsB1 = ldsB0 + 4096;

    const int lane = t & 63;
    const int quad = lane >> 4;
    const int l15  = lane & 15;
    const int w    = t >> 6;
    const int mw0  = (w >> 1) * 64;
    const int nw0  = (w & 1) * 64;
    const char* abase = (const char*)As + (mw0 + l15) * 64 + quad * 16;
    const char* bbase = (const char*)Bs + (nw0 + l15) * 64 + quad * 16;

    f32x4 acc[4][4];
#pragma unroll
    for (int i = 0; i < 4; ++i)
#pragma unroll
        for (int j = 0; j < 4; ++j) acc[i][j] = (f32x4)0.f;

    for (int tap = 0; tap < 9; ++tap) {
        const int dy = tap / 3 - 1, dx = tap % 3 - 1;
        const __bf16* srcA = Am + (long)tap * 131072 + (long)(m0 + rowa) * 512 + c16 * 8;
        const __bf16* srcB0; const __bf16* srcB1;
        bool v0, v1;
        {
            int n = n0 + rowa;
            int x = n & 63, y = n >> 6;
            v0 = !((dx == -1 && x == 0) || (dx == 1 && x == 63) ||
                   (dy == -1 && y == 0) || (dy == 1 && y == 63));
            srcB0 = v0 ? (Xb + (long)(n + dy * 64 + dx) * 512 + c16 * 8)
                       : (zrow + c16 * 8);
            n += 64; x = n & 63; y = n >> 6;
            v1 = !((dx == -1 && x == 0) || (dx == 1 && x == 63) ||
                   (dy == -1 && y == 0) || (dy == 1 && y == 63));
            srcB1 = v1 ? (Xb + (long)(n + dy * 64 + dx) * 512 + c16 * 8)
                       : (zrow + c16 * 8);
        }

        for (int ic0 = 0; ic0 < 512; ic0 += 32) {
            load_lds16(srcA + ic0, ldsA0);
            load_lds16(srcA + ic0 + 32768, ldsA1);
            load_lds16(srcB0 + (v0 ? ic0 : 0), ldsB0);
            load_lds16(srcB1 + (v1 ? ic0 : 0), ldsB1);
            __syncthreads();

            bf16x8 af[4], bfr[4];
#pragma unroll
            for (int i = 0; i < 4; ++i) af[i]  = *(const bf16x8*)(abase + i * 1024);
#pragma unroll
            for (int j = 0; j < 4; ++j) bfr[j] = *(const bf16x8*)(bbase + j * 1024);
#pragma unroll
            for (int i = 0; i < 4; ++i)
#pragma unroll
                for (int j = 0; j < 4; ++j)
                    acc[i][j] = __builtin_amdgcn_mfma_f32_16x16x32_bf16(
                        af[i], bfr[j], acc[i][j], 0, 0, 0);
            __syncthreads();
        }
    }

    const float alpha = (mod ? prd : prr)[0];
    float* outp = conv + (long)mb * 256 * NPIX;
#pragma unroll
    for (int i = 0; i < 4; ++i) {
#pragma unroll
        for (int r = 0; r < 4; ++r) {
            int oc = m0 + mw0 + 16 * i + quad * 4 + r;
            float sc = scA[mod * 256 + oc];
            float sh = shB[mod * 256 + oc];
            float* orow = outp + (long)oc * NPIX;
#pragma unroll
            for (int j = 0; j < 4; ++j) {
                int n = n0 + nw0 + 16 * j + l15;
                float y = acc[i][j][r] * sc + sh;
                y = (y > 0.f) ? y : alpha * y;
                orow[n] = y;
            }
        }
    }
}

// ---------------------------------------------------------------------------
// 1x1-projection MFMA GEMM: C[m][pix] = sum_c W[m][c] * Bt[pix][c] + bias.
// Tile 128m x 128n, K=256 in 8 chunks of 32. grid (32 n, M/128, 4 mb).
// mode 0: bf16 transposed store dstT[pix][32] (q/k; rows >=32 are zero-pad).
// mode 1: bf16 store dstV[c][pix] (v).
// mode 2: fp32 store dstU[oc][pix] = acc + bias + resid (up + input residual).
// ---------------------------------------------------------------------------
__global__ __launch_bounds__(256)
void proj_mfma(const __bf16* __restrict__ Wb, int mstride,
               const __bf16* __restrict__ Bt,
               const float* __restrict__ bias_r, const float* __restrict__ bias_d,
               __bf16* __restrict__ dstT, __bf16* __restrict__ dstV,
               float* __restrict__ dstU,
               const float* __restrict__ resid_r, const float* __restrict__ resid_d,
               int mode)
{
    __shared__ __bf16 As[128 * 32];
    __shared__ __bf16 Bs[128 * 32];

    const int t = threadIdx.x;
    const int n0 = blockIdx.x * 128;
    const int m0 = blockIdx.y * 128;
    const int mb = blockIdx.z;
    const int mod = mb >> 1, b = mb & 1;

    const __bf16* Am = Wb + (long)mod * mstride;
    const __bf16* Bm = Bt + (long)mb * (NPIX * 256);
    const float* bias = mod ? bias_d : bias_r;

    const int rowa = t >> 2, c16 = t & 3;
    char* ldsA0 = (char*)As + (t >> 6) * 1024;
    char* ldsA1 = ldsA0 + 4096;
    char* ldsB0 = (char*)Bs + (t >> 6) * 1024;
    char* ldsB1 = ldsB0 + 4096;
    const __bf16* srcA = Am + (long)(m0 + rowa) * 256 + c16 * 8;
    const __bf16* srcB = Bm + (long)(n0 + rowa) * 256 + c16 * 8;

    const int lane = t & 63, quad = lane >> 4, l15 = lane & 15, w = t >> 6;
    const int mw = (w >> 1) * 64, nw = (w & 1) * 64;
    const char* abase = (const char*)As + (mw + l15) * 64 + quad * 16;
    const char* bbase = (const char*)Bs + (nw + l15) * 64 + quad * 16;

    f32x4 acc[4][4];
#pragma unroll
    for (int i = 0; i < 4; ++i)
#pragma unroll
        for (int j = 0; j < 4; ++j) acc[i][j] = (f32x4)0.f;

    for (int kc = 0; kc < 256; kc += 32) {
        load_lds16(srcA + kc, ldsA0);
        load_lds16(srcA + kc + 16384, ldsA1);   // +64 rows
        load_lds16(srcB + kc, ldsB0);
        load_lds16(srcB + kc + 16384, ldsB1);
        __syncthreads();

        bf16x8 af[4], bfr[4];
#pragma unroll
        for (int i = 0; i < 4; ++i) af[i]  = *(const bf16x8*)(abase + i * 1024);
#pragma unroll
        for (int j = 0; j < 4; ++j) bfr[j] = *(const bf16x8*)(bbase + j * 1024);
#pragma unroll
        for (int i = 0; i < 4; ++i)
#pragma unroll
            for (int j = 0; j < 4; ++j)
                acc[i][j] = __builtin_amdgcn_mfma_f32_16x16x32_bf16(
                    af[i], bfr[j], acc[i][j], 0, 0, 0);
        __syncthreads();
    }

    if (mode == 0) {
        if (mw == 0) {                          // only oc<32 valid
            __bf16* dbase = dstT + (long)mb * (NPIX * 32);
#pragma unroll
            for (int fi = 0; fi < 2; ++fi)
#pragma unroll
                for (int r = 0; r < 4; ++r) {
                    int oc = 16 * fi + quad * 4 + r;
                    float bi = bias[oc];
#pragma unroll
                    for (int fj = 0; fj < 4; ++fj) {
                        int n = n0 + nw + 16 * fj + l15;
                        dbase[(long)n * 32 + oc] = f2b(acc[fi][fj][r] + bi);
                    }
                }
        }
    } else if (mode == 1) {
        __bf16* dv = dstV + (long)mb * (256 * NPIX);
#pragma unroll
        for (int fi = 0; fi < 4; ++fi)
#pragma unroll
            for (int r = 0; r < 4; ++r) {
                int c = m0 + mw + 16 * fi + quad * 4 + r;
                float bi = bias[c];
                __bf16* row = dv + (long)c * NPIX;
#pragma unroll
                for (int fj = 0; fj < 4; ++fj) {
                    int n = n0 + nw + 16 * fj + l15;
                    row[n] = f2b(acc[fi][fj][r] + bi);
                }
            }
    } else {
        float* du = dstU + (long)mod * 4194304 + (long)b * 2097152;
        const float* rs = (mod ? resid_d : resid_r) + (long)b * 2097152;
#pragma unroll
        for (int fi = 0; fi < 4; ++fi)
#pragma unroll
            for (int r = 0; r < 4; ++r) {
                int oc = m0 + mw + 16 * fi + quad * 4 + r;
                float bi = bias[oc];
                const float* rrow = rs + (long)oc * NPIX;
                float* orow = du + (long)oc * NPIX;
#pragma unroll
                for (int fj = 0; fj < 4; ++fj) {
                    int n = n0 + nw + 16 * fj + l15;
                    orow[n] = acc[fi][fj][r] + bi + rrow[n];
                }
            }
    }
}

// ---------------------------------------------------------------------------
// MFMA row stats: S via the SAME bf16 MFMA as attn_pv_mfma (bit-identical),
// two passes (max, sum-exp). grid (32 i-tiles, 4 = o*2+b).
// ---------------------------------------------------------------------------
__global__ __launch_bounds__(256)
void attn_stats_mfma(const __bf16* __restrict__ Qt, const __bf16* __restrict__ Kt,
                     float* __restrict__ rmb, float* __restrict__ rlb)
{
    __shared__ __bf16 Qs[128 * 32];
    __shared__ __bf16 Ks[128 * 32];
    __shared__ float red[2][128];
    __shared__ float mfin[128];

    const int t  = threadIdx.x;
    const int i0 = blockIdx.x * 128;
    const int o  = blockIdx.y >> 1, b = blockIdx.y & 1;
    const int mbK = o * 2 + b, mbQ = (1 - o) * 2 + b;

    const __bf16* Qg = Qt + (long)mbQ * 131072;
    const __bf16* Kg = Kt + (long)mbK * 131072;

    const int lane = t & 63, quad = lane >> 4, l15 = lane & 15, w = t >> 6;
    const int mS = (w >> 1) * 64;
    const int nS = (w & 1) * 64;

    load_lds16((const char*)Qg + (long)i0 * 64 + t * 16, (char*)Qs + (t >> 6) * 1024);
    load_lds16((const char*)Qg + (long)i0 * 64 + 4096 + t * 16,
               (char*)Qs + 4096 + (t >> 6) * 1024);
    __syncthreads();

    bf16x8 qa[4];
#pragma unroll
    for (int fi = 0; fi < 4; ++fi)
        qa[fi] = *(const bf16x8*)((const char*)Qs + (mS + 16 * fi + l15) * 64 + quad * 16);

    const f32x4 zero4 = (f32x4)0.f;
    float mloc[16];
#pragma unroll
    for (int e = 0; e < 16; ++e) mloc[e] = -3.0e38f;

    for (int j0 = 0; j0 < 4096; j0 += 128) {
        __syncthreads();
        load_lds16((const char*)Kg + (long)j0 * 64 + t * 16, (char*)Ks + (t >> 6) * 1024);
        load_lds16((const char*)Kg + (long)j0 * 64 + 4096 + t * 16,
                   (char*)Ks + 4096 + (t >> 6) * 1024);
        __syncthreads();
#pragma unroll
        for (int fj = 0; fj < 4; ++fj) {
            bf16x8 kb = *(const bf16x8*)((const char*)Ks + (nS + 16 * fj + l15) * 64 + quad * 16);
#pragma unroll
            for (int fi = 0; fi < 4; ++fi) {
                f32x4 s = __builtin_amdgcn_mfma_f32_16x16x32_bf16(qa[fi], kb, zero4, 0, 0, 0);
#pragma unroll
                for (int r = 0; r < 4; ++r)
                    mloc[fi * 4 + r] = fmaxf(mloc[fi * 4 + r], s[r]);
            }
        }
    }
#pragma unroll
    for (int d = 1; d < 16; d <<= 1)
#pragma unroll
        for (int e = 0; e < 16; ++e)
            mloc[e] = fmaxf(mloc[e], __shfl_xor(mloc[e], d, 64));
    if (l15 == 0) {
#pragma unroll
        for (int fi = 0; fi < 4; ++fi)
#pragma unroll
            for (int r = 0; r < 4; ++r)
                red[w & 1][mS + 16 * fi + quad * 4 + r] = mloc[fi * 4 + r];
    }
    __syncthreads();
    if (t < 128) mfin[t] = fmaxf(red[0][t], red[1][t]);
    __syncthreads();

    float mi[16];
#pragma unroll
    for (int fi = 0; fi < 4; ++fi)
#pragma unroll
        for (int r = 0; r < 4; ++r)
            mi[fi * 4 + r] = mfin[mS + 16 * fi + quad * 4 + r];
    float sloc[16];
#pragma unroll
    for (int e = 0; e < 16; ++e) sloc[e] = 0.f;

    for (int j0 = 0; j0 < 4096; j0 += 128) {
        __syncthreads();
        load_lds16((const char*)Kg + (long)j0 * 64 + t * 16, (char*)Ks + (t >> 6) * 1024);
        load_lds16((const char*)Kg + (long)j0 * 64 + 4096 + t * 16,
                   (char*)Ks + 4096 + (t >> 6) * 1024);
        __syncthreads();
#pragma unroll
        for (int fj = 0; fj < 4; ++fj) {
            bf16x8 kb = *(const bf16x8*)((const char*)Ks + (nS + 16 * fj + l15) * 64 + quad * 16);
#pragma unroll
            for (int fi = 0; fi < 4; ++fi) {
                f32x4 s = __builtin_amdgcn_mfma_f32_16x16x32_bf16(qa[fi], kb, zero4, 0, 0, 0);
#pragma unroll
                for (int r = 0; r < 4; ++r)
                    sloc[fi * 4 + r] += __expf(s[r] - mi[fi * 4 + r]);
            }
        }
    }
#pragma unroll
    for (int d = 1; d < 16; d <<= 1)
#pragma unroll
        for (int e = 0; e < 16; ++e)
            sloc[e] += __shfl_xor(sloc[e], d, 64);
    if (l15 == 0) {
#pragma unroll
        for (int fi = 0; fi < 4; ++fi)
#pragma unroll
            for (int r = 0; r < 4; ++r)
                red[w & 1][mS + 16 * fi + quad * 4 + r] = sloc[fi * 4 + r];
    }
    __syncthreads();
    if (t < 128) {
        float l = red[0][t] + red[1][t];
        rmb[o * 8192 + b * 4096 + i0 + t] = mfin[t];
        rlb[o * 8192 + b * 4096 + i0 + t] = 1.f / l;
    }
}

// ---------------------------------------------------------------------------
// Fused MFMA PV (verified round 5): S -> P(bf16,LDS) -> acc += V P^T.
// z = gamma*acc + conv. grid (32 i, 2 c, 4 = o*2+b).
// ---------------------------------------------------------------------------
__global__ __launch_bounds__(256)
void attn_pv_mfma(const __bf16* __restrict__ Qt, const __bf16* __restrict__ Kt,
                  const __bf16* __restrict__ Vb, const float* __restrict__ convb,
                  float* __restrict__ zb, const float* __restrict__ rmb,
                  const float* __restrict__ rlb, const float* __restrict__ g_r,
                  const float* __restrict__ g_d)
{
    __shared__ __bf16 Qs[128 * 32];
    __shared__ __bf16 Ks[64 * 32];
    __shared__ __bf16 Vs[2 * 128 * 32];
    __shared__ __bf16 Ps[2 * 128 * 32];

    const int t  = threadIdx.x;
    const int i0 = blockIdx.x * 128;
    const int c0 = blockIdx.y * 128;
    const int o  = blockIdx.z >> 1, b = blockIdx.z & 1;
    const int mbK = o * 2 + b, mbQ = (1 - o) * 2 + b;

    const __bf16* Qg = Qt + (long)mbQ * 131072;
    const __bf16* Kg = Kt + (long)mbK * 131072;
    const __bf16* Vg = Vb + (long)mbK * 1048576;
    const float* cvg = convb + (long)mbK * 1048576;
    float* zg = zb + (long)mbK * 1048576;
    const float* rm = rmb + o * 8192 + b * 4096;
    const float* rl = rlb + o * 8192 + b * 4096;

    const int lane = t & 63, quad = lane >> 4, l15 = lane & 15, w = t >> 6;
    const int mw = (w >> 1) * 64;
    const int nw = (w & 1) * 64;
    const int mS = (w >> 1) * 64;
    const int nS = (w & 1) * 32;
    const int ksP = w & 1;

    load_lds16((const char*)Qg + (long)i0 * 64 + t * 16, (char*)Qs + (t >> 6) * 1024);
    load_lds16((const char*)Qg + (long)i0 * 64 + 4096 + t * 16,
               (char*)Qs + 4096 + (t >> 6) * 1024);

    float mlv[16], rlv[16];
#pragma unroll
    for (int fi = 0; fi < 4; ++fi)
#pragma unroll
        for (int r = 0; r < 4; ++r) {
            int i = i0 + mS + 16 * fi + quad * 4 + r;
            mlv[fi * 4 + r] = rm[i];
            rlv[fi * 4 + r] = rl[i];
        }

    f32x4 acc[4][4];
#pragma unroll
    for (int i = 0; i < 4; ++i)
#pragma unroll
        for (int j = 0; j < 4; ++j) acc[i][j] = (f32x4)0.f;
    const f32x4 zero4 = (f32x4)0.f;

    for (int j0 = 0; j0 < 4096; j0 += 64) {
        __syncthreads();
        load_lds16((const char*)Kg + (long)j0 * 64 + t * 16, (char*)Ks + (t >> 6) * 1024);
#pragma unroll
        for (int ii = 0; ii < 4; ++ii) {
            int s = ii * 256 + t;
            int ks = s >> 9, cc = (s >> 2) & 127, blk = s & 3;
            load_lds16((const char*)Vg + (long)(c0 + cc) * 8192 + (j0 + ks * 32) * 2 + blk * 16,
                       (char*)Vs + ii * 4096 + (t >> 6) * 1024);
        }
        __syncthreads();

        bf16x8 qa[4], kb2[2];
#pragma unroll
        for (int fi = 0; fi < 4; ++fi)
            qa[fi] = *(const bf16x8*)((const char*)Qs + (mS + 16 * fi + l15) * 64 + quad * 16);
#pragma unroll
        for (int fj = 0; fj < 2; ++fj)
            kb2[fj] = *(const bf16x8*)((const char*)Ks + (nS + 16 * fj + l15) * 64 + quad * 16);
        f32x4 sA[4][2];
#pragma unroll
        for (int fi = 0; fi < 4; ++fi)
#pragma unroll
            for (int fj = 0; fj < 2; ++fj)
                sA[fi][fj] = __builtin_amdgcn_mfma_f32_16x16x32_bf16(
                    qa[fi], kb2[fj], zero4, 0, 0, 0);

        __bf16* prow = Ps + ksP * 4096;
#pragma unroll
        for (int fi = 0; fi < 4; ++fi)
#pragma unroll
            for (int fj = 0; fj < 2; ++fj) {
                int jl = 16 * fj + l15;
#pragma unroll
                for (int r = 0; r < 4; ++r) {
                    float p = __expf(sA[fi][fj][r] - mlv[fi * 4 + r]) * rlv[fi * 4 + r];
                    prow[(mS + 16 * fi + quad * 4 + r) * 32 + jl] = f2b(p);
                }
            }
        __syncthreads();

#pragma unroll
        for (int ks = 0; ks < 2; ++ks) {
            bf16x8 va[4], pb[4];
#pragma unroll
            for (int fi = 0; fi < 4; ++fi)
                va[fi] = *(const bf16x8*)((const char*)Vs + ks * 8192 +
                                          (mw + 16 * fi + l15) * 64 + quad * 16);
#pragma unroll
            for (int fj = 0; fj < 4; ++fj)
                pb[fj] = *(const bf16x8*)((const char*)Ps + ks * 8192 +
                                          (nw + 16 * fj + l15) * 64 + quad * 16);
#pragma unroll
            for (int fi = 0; fi < 4; ++fi)
#pragma unroll
                for (int fj = 0; fj < 4; ++fj)
                    acc[fi][fj] = __builtin_amdgcn_mfma_f32_16x16x32_bf16(
                        va[fi], pb[fj], acc[fi][fj], 0, 0, 0);
        }
    }

    const float gamma = (o ? g_d : g_r)[0];
#pragma unroll
    for (int fi = 0; fi < 4; ++fi) {
#pragma unroll
        for (int r = 0; r < 4; ++r) {
            int c = c0 + mw + 16 * fi + quad * 4 + r;
            const float* crow = cvg + (long)c * 4096;
            float* zr = zg + (long)c * 4096;
#pragma unroll
            for (int fj = 0; fj < 4; ++fj) {
                int i = i0 + nw + 16 * fj + l15;
                zr[i] = gamma * acc[fi][fj][r] + crow[i];
            }
        }
    }
}

// ---------------------------------------------------------------------------
// Host launcher
// ---------------------------------------------------------------------------
// ws layout (float slots):
//   conv fp32 [4mb][256][4096] @ 0           (4,194,304)
//   z    fp32 [4mb][256][4096] @ 4,194,304   (4,194,304)
//   rowm [2o][2b][4096]        @ 8,388,608   (16,384)
//   rowl                        @ 8,404,992  (16,384)
//   scA  [2][256]              @ 8,421,376   (512)
//   shB  [2][256]              @ 8,421,888   (512)
//   zrow (512 bf16)            @ 8,422,400   (256)
//   Wt   bf16 [2][9][256][512] @ 8,422,656   (1,179,648)
//   Xp   bf16 [4][4096][512]   @ 9,602,304   (4,194,304)
//   Qt   bf16 [4][4096][32]    @ 13,796,608  (262,144)
//   Kt   bf16 [4][4096][32]    @ 14,058,752  (262,144)
//   Vbb  bf16 [4][256][4096]   @ 14,320,896  (2,097,152)
//   Ct   bf16 [4][4096][256]   @ 16,418,048  (2,097,152)
//   Zt   bf16 [4][4096][256]   @ 18,515,200  (2,097,152)
//   Wq   bf16 [2][128][256]    @ 20,612,352  (32,768)
//   Wk   bf16 [2][128][256]    @ 20,645,120  (32,768)
//   Wv   bf16 [2][256][256]    @ 20,677,888  (65,536)
//   Wu   bf16 [2][512][256]    @ 20,743,424  (131,072)
//   total 20,874,496 floats = 83.5 MiB
extern "C" void kernel_launch(void* const* d_in, const int* in_sizes, int n_in,
                              void* d_out, int out_size, void* d_ws, size_t ws_size,
                              hipStream_t stream)
{
    const float* in_rgb = (const float*)d_in[0];
    const float* in_dsm = (const float*)d_in[1];
    auto P = [&](int i) { return (const float*)d_in[i]; };

    float* ws   = (float*)d_ws;
    float* conv = ws;
    float* zb_  = ws + 4194304;
    float* rmb  = ws + 8388608;
    float* rlb  = ws + 8404992;
    float* scA  = ws + 8421376;
    float* shB  = ws + 8421888;
    __bf16* zrow = (__bf16*)(ws + 8422400);
    __bf16* Wt   = (__bf16*)(ws + 8422656);
    __bf16* Xp   = (__bf16*)(ws + 9602304);
    __bf16* Qt   = (__bf16*)(ws + 13796608);
    __bf16* Kt   = (__bf16*)(ws + 14058752);
    __bf16* Vbb  = (__bf16*)(ws + 14320896);
    __bf16* Ct   = (__bf16*)(ws + 16418048);
    __bf16* Zt   = (__bf16*)(ws + 18515200);
    __bf16* Wq   = (__bf16*)(ws + 20612352);
    __bf16* Wk   = (__bf16*)(ws + 20645120);
    __bf16* Wv   = (__bf16*)(ws + 20677888);
    __bf16* Wu   = (__bf16*)(ws + 20743424);

    // prep
    prep_w<<<2307, 256, 0, stream>>>(
        P(2), P(18), P(3), P(4), P(5), P(6), P(7),
        P(19), P(20), P(21), P(22), P(23),
        Wt, scA, shB, zrow);
    prep_gw<<<512, 256, 0, stream>>>(
        P(9), P(25), P(11), P(27), P(13), P(29), P(15), P(31),
        Wq, Wk, Wv, Wu);
    xpose<<<dim3(128, 16, 4), 256, 0, stream>>>(in_rgb, in_dsm, Xp);

    // conv3x3 + BN + PReLU
    conv_mfma<<<dim3(32, 2, 4), 256, 0, stream>>>(
        Wt, Xp, zrow, scA, shB, P(8), P(24), conv);
    t256<<<dim3(128, 8, 4), 256, 0, stream>>>(conv, Ct);

    // q/k/v projections (MFMA, bf16 outputs in attention layouts)
    proj_mfma<<<dim3(32, 1, 4), 256, 0, stream>>>(
        Wq, 32768, Ct, P(10), P(26), Qt, nullptr, nullptr, nullptr, nullptr, 0);
    proj_mfma<<<dim3(32, 1, 4), 256, 0, stream>>>(
        Wk, 32768, Ct, P(12), P(28), Kt, nullptr, nullptr, nullptr, nullptr, 0);
    proj_mfma<<<dim3(32, 2, 4), 256, 0, stream>>>(
        Wv, 65536, Ct, P(14), P(30), nullptr, Vbb, nullptr, nullptr, nullptr, 1);

    // softmax stats (bit-identical S path to attn_pv_mfma)
    attn_stats_mfma<<<dim3(32, 4), 256, 0, stream>>>(Qt, Kt, rmb, rlb);

    // fused PV + gamma-gate + conv residual -> z
    attn_pv_mfma<<<dim3(32, 2, 4), 256, 0, stream>>>(
        Qt, Kt, Vbb, conv, zb_, rmb, rlb, P(17), P(33));
    t256<<<dim3(128, 8, 4), 256, 0, stream>>>(zb_, Zt);

    // up projection + input residual -> fp32 out
    proj_mfma<<<dim3(32, 4, 4), 256, 0, stream>>>(
        Wu, 131072, Zt, P(16), P(32), nullptr, nullptr, (float*)d_out,
        in_rgb, in_dsm, 2);
}

// Round 7
// 405.414 us; speedup vs baseline: 6.4728x; 1.1760x over previous
//
#include <hip/hip_runtime.h>
#include <hip/hip_bf16.h>
#include <stdint.h>

// fp32 I/O. Conv3x3, 1x1 projections, and attention run as bf16 MFMA.
// Softmax stats (m,l) and P come from the SAME bf16 MFMA S path (unscaled
// attention -> near-argmax softmax; any S mismatch scales o by exp(dS)).
// Round 7: every MFMA kernel split to >=512 blocks (2 blocks/CU) so barrier
// drains overlap across co-resident blocks (1 block/CU was MfmaUtil 13%).

constexpr int CINCH = 512;
constexpr int NPIX  = 4096;   // 64*64

typedef __bf16 bf16x8 __attribute__((ext_vector_type(8)));
typedef __bf16 bf16x4 __attribute__((ext_vector_type(4)));
typedef float  f32x4  __attribute__((ext_vector_type(4)));

__device__ __forceinline__ __bf16 f2b(float f) {
    __hip_bfloat16 h = __float2bfloat16(f);
    return *reinterpret_cast<__bf16*>(&h);
}

__device__ __forceinline__ void load_lds16(const void* g, void* l) {
    __builtin_amdgcn_global_load_lds(
        (const __attribute__((address_space(1))) unsigned int*)(uintptr_t)g,
        (__attribute__((address_space(3))) unsigned int*)(uintptr_t)l,
        16, 0, 0);
}

// ---------------------------------------------------------------------------
// Prep A: conv weights fp32 [oc][ic][9] -> Wt bf16 [mod][tap][oc][ic];
// BN scale/shift tables; zero row. grid 2307 x 256.
// ---------------------------------------------------------------------------
__global__ __launch_bounds__(256)
void prep_w(const float* __restrict__ w_r, const float* __restrict__ w_d,
            const float* __restrict__ cb_r, const float* __restrict__ bg_r,
            const float* __restrict__ bb_r, const float* __restrict__ bm_r,
            const float* __restrict__ bv_r,
            const float* __restrict__ cb_d, const float* __restrict__ bg_d,
            const float* __restrict__ bb_d, const float* __restrict__ bm_d,
            const float* __restrict__ bv_d,
            __bf16* __restrict__ Wt, float* __restrict__ scA,
            float* __restrict__ shB, __bf16* __restrict__ zrow)
{
    const int t = threadIdx.x;
    const int blk = blockIdx.x;
    if (blk < 2304) {
        int gid = blk * 1024 + t * 4;
        int mod = gid >= 1179648;
        int o2  = gid - mod * 1179648;
        int tap = o2 >> 17;
        int r   = o2 & 131071;
        int oc  = r >> 9;
        int ic  = r & 511;
        const float* wsrc = mod ? w_d : w_r;
        long base = ((long)(oc * 512 + ic)) * 9 + tap;
        bf16x4 v;
        v.x = f2b(wsrc[base]);
        v.y = f2b(wsrc[base + 9]);
        v.z = f2b(wsrc[base + 18]);
        v.w = f2b(wsrc[base + 27]);
        *(bf16x4*)&Wt[gid] = v;
    } else if (blk == 2304) {
        unsigned short* z = (unsigned short*)zrow;
        z[t] = 0; z[t + 256] = 0;
    } else {
        int mod = blk - 2305;
        const float* cb = mod ? cb_d : cb_r;
        const float* bg = mod ? bg_d : bg_r;
        const float* bb = mod ? bb_d : bb_r;
        const float* bm = mod ? bm_d : bm_r;
        const float* bv = mod ? bv_d : bv_r;
        int oc = t;
        float sc = bg[oc] * rsqrtf(bv[oc] + 1e-5f);
        scA[mod * 256 + oc] = sc;
        shB[mod * 256 + oc] = (cb[oc] - bm[oc]) * sc + bb[oc];
    }
}

// ---------------------------------------------------------------------------
// Prep B: projection weights fp32 -> bf16. Wq/Wk padded to 128 rows (zeros).
// ---------------------------------------------------------------------------
__global__ __launch_bounds__(256)
void prep_gw(const float* __restrict__ qw_r, const float* __restrict__ qw_d,
             const float* __restrict__ kw_r, const float* __restrict__ kw_d,
             const float* __restrict__ vw_r, const float* __restrict__ vw_d,
             const float* __restrict__ uw_r, const float* __restrict__ uw_d,
             __bf16* __restrict__ Wq, __bf16* __restrict__ Wk,
             __bf16* __restrict__ Wv, __bf16* __restrict__ Wu)
{
    int gid = blockIdx.x * 1024 + threadIdx.x * 4;
    __bf16* dst;
    float4 f = make_float4(0.f, 0.f, 0.f, 0.f);
    if (gid < 65536) {
        int mod = gid >> 15, e = gid & 32767;
        dst = Wq + gid;
        if (e < 8192) f = *(const float4*)((mod ? qw_d : qw_r) + e);
    } else if (gid < 131072) {
        int g = gid - 65536;
        int mod = g >> 15, e = g & 32767;
        dst = Wk + g;
        if (e < 8192) f = *(const float4*)((mod ? kw_d : kw_r) + e);
    } else if (gid < 262144) {
        int g = gid - 131072;
        int mod = g >> 16, e = g & 65535;
        dst = Wv + g;
        f = *(const float4*)((mod ? vw_d : vw_r) + e);
    } else {
        int g = gid - 262144;
        int mod = g >> 17, e = g & 131071;
        dst = Wu + g;
        f = *(const float4*)((mod ? uw_d : uw_r) + e);
    }
    bf16x4 o; o.x = f2b(f.x); o.y = f2b(f.y); o.z = f2b(f.z); o.w = f2b(f.w);
    *(bf16x4*)dst = o;
}

// ---------------------------------------------------------------------------
// Prep C: X fp32 [mod][b][512][4096] -> Xp bf16 [modb][4096pix][512ic]
// ---------------------------------------------------------------------------
__global__ __launch_bounds__(256)
void xpose(const float* __restrict__ inr, const float* __restrict__ ind,
           __bf16* __restrict__ Xp)
{
    __shared__ float tile[32][33];
    const int t = threadIdx.x;
    const int p0 = blockIdx.x * 32;
    const int ic0 = blockIdx.y * 32;
    const int mb = blockIdx.z;
    const int mod = mb >> 1, b = mb & 1;
    const float* src = (mod ? ind : inr) + (long)b * CINCH * NPIX;

    int i = t >> 3, j4 = (t & 7) * 4;
    float4 v = *(const float4*)&src[(long)(ic0 + i) * NPIX + p0 + j4];
    tile[i][j4 + 0] = v.x; tile[i][j4 + 1] = v.y;
    tile[i][j4 + 2] = v.z; tile[i][j4 + 3] = v.w;
    __syncthreads();
    int j = t >> 3, i4 = (t & 7) * 4;
    bf16x4 o;
    o.x = f2b(tile[i4 + 0][j]);
    o.y = f2b(tile[i4 + 1][j]);
    o.z = f2b(tile[i4 + 2][j]);
    o.w = f2b(tile[i4 + 3][j]);
    *(bf16x4*)&Xp[((long)mb * NPIX + p0 + j) * 512 + ic0 + i4] = o;
}

// ---------------------------------------------------------------------------
// fp32 [mb][256][4096] -> bf16 transposed [mb][4096][256]. grid (128, 8, 4).
// ---------------------------------------------------------------------------
__global__ __launch_bounds__(256)
void t256(const float* __restrict__ src, __bf16* __restrict__ dst)
{
    __shared__ float tile[32][33];
    const int t = threadIdx.x;
    const int p0 = blockIdx.x * 32;
    const int c0 = blockIdx.y * 32;
    const int mb = blockIdx.z;
    const float* s = src + (long)mb * 256 * NPIX;
    __bf16* d = dst + (long)mb * NPIX * 256;

    int i = t >> 3, j4 = (t & 7) * 4;
    float4 v = *(const float4*)&s[(long)(c0 + i) * NPIX + p0 + j4];
    tile[i][j4 + 0] = v.x; tile[i][j4 + 1] = v.y;
    tile[i][j4 + 2] = v.z; tile[i][j4 + 3] = v.w;
    __syncthreads();
    int j = t >> 3, i4 = (t & 7) * 4;
    bf16x4 o;
    o.x = f2b(tile[i4 + 0][j]); o.y = f2b(tile[i4 + 1][j]);
    o.z = f2b(tile[i4 + 2][j]); o.w = f2b(tile[i4 + 3][j]);
    *(bf16x4*)&d[((long)(p0 + j)) * 256 + c0 + i4] = o;
}

// ---------------------------------------------------------------------------
// Conv3x3 implicit-GEMM MFMA, 64oc x 128pix tile (2 blocks/CU).
// Wave layout: all waves share the 64 oc; wave w covers pix [w*32, w*32+32).
// grid (32 pixtiles, 4 octiles, 4 mb). Same K-order as round 3 (bit-identical).
// ---------------------------------------------------------------------------
__global__ __launch_bounds__(256)
void conv_mfma(const __bf16* __restrict__ Wt, const __bf16* __restrict__ Xp,
               const __bf16* __restrict__ zrow, const float* __restrict__ scA,
               const float* __restrict__ shB, const float* __restrict__ prr,
               const float* __restrict__ prd, float* __restrict__ conv)
{
    __shared__ __bf16 As[64 * 32];    // 4KB  [oc][32ic]
    __shared__ __bf16 Bs[128 * 32];   // 8KB  [pix][32ic]

    const int t = threadIdx.x;
    const int n0 = blockIdx.x * 128;
    const int m0 = blockIdx.y * 64;
    const int mb = blockIdx.z;
    const int mod = mb >> 1;

    const __bf16* Am = Wt + (long)mod * 9 * 256 * 512;
    const __bf16* Xb = Xp + (long)mb * NPIX * 512;

    const int rowa = t >> 2;          // 0..63
    const int c16  = t & 3;
    char* ldsA  = (char*)As + (t >> 6) * 1024;
    char* ldsB0 = (char*)Bs + (t >> 6) * 1024;
    char* ldsB1 = ldsB0 + 4096;

    const int lane = t & 63, quad = lane >> 4, l15 = lane & 15, w = t >> 6;
    const int nw0 = w * 32;
    const char* abase = (const char*)As + l15 * 64 + quad * 16;
    const char* bbase = (const char*)Bs + (nw0 + l15) * 64 + quad * 16;

    f32x4 acc[4][2];
#pragma unroll
    for (int i = 0; i < 4; ++i)
#pragma unroll
        for (int j = 0; j < 2; ++j) acc[i][j] = (f32x4)0.f;

    for (int tap = 0; tap < 9; ++tap) {
        const int dy = tap / 3 - 1, dx = tap % 3 - 1;
        const __bf16* srcA = Am + (long)tap * 131072 + (long)(m0 + rowa) * 512 + c16 * 8;
        const __bf16* srcB0; const __bf16* srcB1;
        bool v0, v1;
        {
            int n = n0 + rowa;
            int x = n & 63, y = n >> 6;
            v0 = !((dx == -1 && x == 0) || (dx == 1 && x == 63) ||
                   (dy == -1 && y == 0) || (dy == 1 && y == 63));
            srcB0 = v0 ? (Xb + (long)(n + dy * 64 + dx) * 512 + c16 * 8)
                       : (zrow + c16 * 8);
            n += 64; x = n & 63; y = n >> 6;
            v1 = !((dx == -1 && x == 0) || (dx == 1 && x == 63) ||
                   (dy == -1 && y == 0) || (dy == 1 && y == 63));
            srcB1 = v1 ? (Xb + (long)(n + dy * 64 + dx) * 512 + c16 * 8)
                       : (zrow + c16 * 8);
        }

        for (int ic0 = 0; ic0 < 512; ic0 += 32) {
            load_lds16(srcA + ic0, ldsA);
            load_lds16(srcB0 + (v0 ? ic0 : 0), ldsB0);
            load_lds16(srcB1 + (v1 ? ic0 : 0), ldsB1);
            __syncthreads();

            bf16x8 af[4], bfr[2];
#pragma unroll
            for (int i = 0; i < 4; ++i) af[i]  = *(const bf16x8*)(abase + i * 1024);
#pragma unroll
            for (int j = 0; j < 2; ++j) bfr[j] = *(const bf16x8*)(bbase + j * 1024);
#pragma unroll
            for (int i = 0; i < 4; ++i)
#pragma unroll
                for (int j = 0; j < 2; ++j)
                    acc[i][j] = __builtin_amdgcn_mfma_f32_16x16x32_bf16(
                        af[i], bfr[j], acc[i][j], 0, 0, 0);
            __syncthreads();
        }
    }

    const float alpha = (mod ? prd : prr)[0];
    float* outp = conv + (long)mb * 256 * NPIX;
#pragma unroll
    for (int i = 0; i < 4; ++i) {
#pragma unroll
        for (int r = 0; r < 4; ++r) {
            int oc = m0 + 16 * i + quad * 4 + r;
            float sc = scA[mod * 256 + oc];
            float sh = shB[mod * 256 + oc];
            float* orow = outp + (long)oc * NPIX;
#pragma unroll
            for (int j = 0; j < 2; ++j) {
                int n = n0 + nw0 + 16 * j + l15;
                float y = acc[i][j][r] * sc + sh;
                y = (y > 0.f) ? y : alpha * y;
                orow[n] = y;
            }
        }
    }
}

// ---------------------------------------------------------------------------
// 1x1-projection MFMA GEMM (verified round 6).
// ---------------------------------------------------------------------------
__global__ __launch_bounds__(256)
void proj_mfma(const __bf16* __restrict__ Wb, int mstride,
               const __bf16* __restrict__ Bt,
               const float* __restrict__ bias_r, const float* __restrict__ bias_d,
               __bf16* __restrict__ dstT, __bf16* __restrict__ dstV,
               float* __restrict__ dstU,
               const float* __restrict__ resid_r, const float* __restrict__ resid_d,
               int mode)
{
    __shared__ __bf16 As[128 * 32];
    __shared__ __bf16 Bs[128 * 32];

    const int t = threadIdx.x;
    const int n0 = blockIdx.x * 128;
    const int m0 = blockIdx.y * 128;
    const int mb = blockIdx.z;
    const int mod = mb >> 1, b = mb & 1;

    const __bf16* Am = Wb + (long)mod * mstride;
    const __bf16* Bm = Bt + (long)mb * (NPIX * 256);
    const float* bias = mod ? bias_d : bias_r;

    const int rowa = t >> 2, c16 = t & 3;
    char* ldsA0 = (char*)As + (t >> 6) * 1024;
    char* ldsA1 = ldsA0 + 4096;
    char* ldsB0 = (char*)Bs + (t >> 6) * 1024;
    char* ldsB1 = ldsB0 + 4096;
    const __bf16* srcA = Am + (long)(m0 + rowa) * 256 + c16 * 8;
    const __bf16* srcB = Bm + (long)(n0 + rowa) * 256 + c16 * 8;

    const int lane = t & 63, quad = lane >> 4, l15 = lane & 15, w = t >> 6;
    const int mw = (w >> 1) * 64, nw = (w & 1) * 64;
    const char* abase = (const char*)As + (mw + l15) * 64 + quad * 16;
    const char* bbase = (const char*)Bs + (nw + l15) * 64 + quad * 16;

    f32x4 acc[4][4];
#pragma unroll
    for (int i = 0; i < 4; ++i)
#pragma unroll
        for (int j = 0; j < 4; ++j) acc[i][j] = (f32x4)0.f;

    for (int kc = 0; kc < 256; kc += 32) {
        load_lds16(srcA + kc, ldsA0);
        load_lds16(srcA + kc + 16384, ldsA1);
        load_lds16(srcB + kc, ldsB0);
        load_lds16(srcB + kc + 16384, ldsB1);
        __syncthreads();

        bf16x8 af[4], bfr[4];
#pragma unroll
        for (int i = 0; i < 4; ++i) af[i]  = *(const bf16x8*)(abase + i * 1024);
#pragma unroll
        for (int j = 0; j < 4; ++j) bfr[j] = *(const bf16x8*)(bbase + j * 1024);
#pragma unroll
        for (int i = 0; i < 4; ++i)
#pragma unroll
            for (int j = 0; j < 4; ++j)
                acc[i][j] = __builtin_amdgcn_mfma_f32_16x16x32_bf16(
                    af[i], bfr[j], acc[i][j], 0, 0, 0);
        __syncthreads();
    }

    if (mode == 0) {
        if (mw == 0) {
            __bf16* dbase = dstT + (long)mb * (NPIX * 32);
#pragma unroll
            for (int fi = 0; fi < 2; ++fi)
#pragma unroll
                for (int r = 0; r < 4; ++r) {
                    int oc = 16 * fi + quad * 4 + r;
                    float bi = bias[oc];
#pragma unroll
                    for (int fj = 0; fj < 4; ++fj) {
                        int n = n0 + nw + 16 * fj + l15;
                        dbase[(long)n * 32 + oc] = f2b(acc[fi][fj][r] + bi);
                    }
                }
        }
    } else if (mode == 1) {
        __bf16* dv = dstV + (long)mb * (256 * NPIX);
#pragma unroll
        for (int fi = 0; fi < 4; ++fi)
#pragma unroll
            for (int r = 0; r < 4; ++r) {
                int c = m0 + mw + 16 * fi + quad * 4 + r;
                float bi = bias[c];
                __bf16* row = dv + (long)c * NPIX;
#pragma unroll
                for (int fj = 0; fj < 4; ++fj) {
                    int n = n0 + nw + 16 * fj + l15;
                    row[n] = f2b(acc[fi][fj][r] + bi);
                }
            }
    } else {
        float* du = dstU + (long)mod * 4194304 + (long)b * 2097152;
        const float* rs = (mod ? resid_d : resid_r) + (long)b * 2097152;
#pragma unroll
        for (int fi = 0; fi < 4; ++fi)
#pragma unroll
            for (int r = 0; r < 4; ++r) {
                int oc = m0 + mw + 16 * fi + quad * 4 + r;
                float bi = bias[oc];
                const float* rrow = rs + (long)oc * NPIX;
                float* orow = du + (long)oc * NPIX;
#pragma unroll
                for (int fj = 0; fj < 4; ++fj) {
                    int n = n0 + nw + 16 * fj + l15;
                    orow[n] = acc[fi][fj][r] + bi + rrow[n];
                }
            }
    }
}

// ---------------------------------------------------------------------------
// MFMA row stats over a j-SEGMENT [seg*2048, seg*2048+2048): partial m, l
// (raw sum). Same bf16 MFMA S as attn_pv_mfma. grid (32 i, 4 mbo, 2 seg).
// ---------------------------------------------------------------------------
__global__ __launch_bounds__(256)
void attn_stats_mfma(const __bf16* __restrict__ Qt, const __bf16* __restrict__ Kt,
                     float* __restrict__ rmp, float* __restrict__ rlp)
{
    __shared__ __bf16 Qs[128 * 32];
    __shared__ __bf16 Ks[128 * 32];
    __shared__ float red[2][128];
    __shared__ float mfin[128];

    const int t  = threadIdx.x;
    const int i0 = blockIdx.x * 128;
    const int mbo = blockIdx.y;
    const int o  = mbo >> 1, b = mbo & 1;
    const int seg = blockIdx.z;
    const int jbase = seg * 2048;
    const int mbK = o * 2 + b, mbQ = (1 - o) * 2 + b;

    const __bf16* Qg = Qt + (long)mbQ * 131072;
    const __bf16* Kg = Kt + (long)mbK * 131072;

    const int lane = t & 63, quad = lane >> 4, l15 = lane & 15, w = t >> 6;
    const int mS = (w >> 1) * 64;
    const int nS = (w & 1) * 64;

    load_lds16((const char*)Qg + (long)i0 * 64 + t * 16, (char*)Qs + (t >> 6) * 1024);
    load_lds16((const char*)Qg + (long)i0 * 64 + 4096 + t * 16,
               (char*)Qs + 4096 + (t >> 6) * 1024);
    __syncthreads();

    bf16x8 qa[4];
#pragma unroll
    for (int fi = 0; fi < 4; ++fi)
        qa[fi] = *(const bf16x8*)((const char*)Qs + (mS + 16 * fi + l15) * 64 + quad * 16);

    const f32x4 zero4 = (f32x4)0.f;
    float mloc[16];
#pragma unroll
    for (int e = 0; e < 16; ++e) mloc[e] = -3.0e38f;

    for (int j0 = jbase; j0 < jbase + 2048; j0 += 128) {
        __syncthreads();
        load_lds16((const char*)Kg + (long)j0 * 64 + t * 16, (char*)Ks + (t >> 6) * 1024);
        load_lds16((const char*)Kg + (long)j0 * 64 + 4096 + t * 16,
                   (char*)Ks + 4096 + (t >> 6) * 1024);
        __syncthreads();
#pragma unroll
        for (int fj = 0; fj < 4; ++fj) {
            bf16x8 kb = *(const bf16x8*)((const char*)Ks + (nS + 16 * fj + l15) * 64 + quad * 16);
#pragma unroll
            for (int fi = 0; fi < 4; ++fi) {
                f32x4 s = __builtin_amdgcn_mfma_f32_16x16x32_bf16(qa[fi], kb, zero4, 0, 0, 0);
#pragma unroll
                for (int r = 0; r < 4; ++r)
                    mloc[fi * 4 + r] = fmaxf(mloc[fi * 4 + r], s[r]);
            }
        }
    }
#pragma unroll
    for (int d = 1; d < 16; d <<= 1)
#pragma unroll
        for (int e = 0; e < 16; ++e)
            mloc[e] = fmaxf(mloc[e], __shfl_xor(mloc[e], d, 64));
    if (l15 == 0) {
#pragma unroll
        for (int fi = 0; fi < 4; ++fi)
#pragma unroll
            for (int r = 0; r < 4; ++r)
                red[w & 1][mS + 16 * fi + quad * 4 + r] = mloc[fi * 4 + r];
    }
    __syncthreads();
    if (t < 128) mfin[t] = fmaxf(red[0][t], red[1][t]);
    __syncthreads();

    float mi[16];
#pragma unroll
    for (int fi = 0; fi < 4; ++fi)
#pragma unroll
        for (int r = 0; r < 4; ++r)
            mi[fi * 4 + r] = mfin[mS + 16 * fi + quad * 4 + r];
    float sloc[16];
#pragma unroll
    for (int e = 0; e < 16; ++e) sloc[e] = 0.f;

    for (int j0 = jbase; j0 < jbase + 2048; j0 += 128) {
        __syncthreads();
        load_lds16((const char*)Kg + (long)j0 * 64 + t * 16, (char*)Ks + (t >> 6) * 1024);
        load_lds16((const char*)Kg + (long)j0 * 64 + 4096 + t * 16,
                   (char*)Ks + 4096 + (t >> 6) * 1024);
        __syncthreads();
#pragma unroll
        for (int fj = 0; fj < 4; ++fj) {
            bf16x8 kb = *(const bf16x8*)((const char*)Ks + (nS + 16 * fj + l15) * 64 + quad * 16);
#pragma unroll
            for (int fi = 0; fi < 4; ++fi) {
                f32x4 s = __builtin_amdgcn_mfma_f32_16x16x32_bf16(qa[fi], kb, zero4, 0, 0, 0);
#pragma unroll
                for (int r = 0; r < 4; ++r)
                    sloc[fi * 4 + r] += __expf(s[r] - mi[fi * 4 + r]);
            }
        }
    }
#pragma unroll
    for (int d = 1; d < 16; d <<= 1)
#pragma unroll
        for (int e = 0; e < 16; ++e)
            sloc[e] += __shfl_xor(sloc[e], d, 64);
    if (l15 == 0) {
#pragma unroll
        for (int fi = 0; fi < 4; ++fi)
#pragma unroll
            for (int r = 0; r < 4; ++r)
                red[w & 1][mS + 16 * fi + quad * 4 + r] = sloc[fi * 4 + r];
    }
    __syncthreads();
    if (t < 128) {
        rmp[seg * 16384 + mbo * 4096 + i0 + t] = mfin[t];
        rlp[seg * 16384 + mbo * 4096 + i0 + t] = red[0][t] + red[1][t];
    }
}

// ---------------------------------------------------------------------------
// Merge 2-segment stats: m = max, rl = 1/(l0 e^{m0-m} + l1 e^{m1-m}).
// grid 64 x 256 (16384 rows).
// ---------------------------------------------------------------------------
__global__ __launch_bounds__(256)
void stats_merge(const float* __restrict__ rmp, const float* __restrict__ rlp,
                 float* __restrict__ rmb, float* __restrict__ rlb)
{
    int idx = blockIdx.x * 256 + threadIdx.x;
    float m0 = rmp[idx], m1 = rmp[16384 + idx];
    float l0 = rlp[idx], l1 = rlp[16384 + idx];
    float m = fmaxf(m0, m1);
    float l = l0 * __expf(m0 - m) + l1 * __expf(m1 - m);
    rmb[idx] = m;
    rlb[idx] = 1.f / l;
}

// ---------------------------------------------------------------------------
// Fused MFMA PV over a j-SEGMENT: partial acc (raw fp32) -> part0/part1.
// grid (32 i, 2 c, 8 = seg*4 + mb). 512 blocks = 2/CU.
// ---------------------------------------------------------------------------
__global__ __launch_bounds__(256)
void attn_pv_mfma(const __bf16* __restrict__ Qt, const __bf16* __restrict__ Kt,
                  const __bf16* __restrict__ Vb,
                  float* __restrict__ part0, float* __restrict__ part1,
                  const float* __restrict__ rmb, const float* __restrict__ rlb)
{
    __shared__ __bf16 Qs[128 * 32];
    __shared__ __bf16 Ks[64 * 32];
    __shared__ __bf16 Vs[2 * 128 * 32];
    __shared__ __bf16 Ps[2 * 128 * 32];

    const int t  = threadIdx.x;
    const int i0 = blockIdx.x * 128;
    const int c0 = blockIdx.y * 128;
    const int zb = blockIdx.z;
    const int seg = zb >> 2, mb = zb & 3;
    const int o  = mb >> 1, b = mb & 1;
    const int mbK = mb, mbQ = (1 - o) * 2 + b;
    const int jbase = seg * 2048;

    const __bf16* Qg = Qt + (long)mbQ * 131072;
    const __bf16* Kg = Kt + (long)mbK * 131072;
    const __bf16* Vg = Vb + (long)mbK * 1048576;
    const float* rm = rmb + mb * 4096;
    const float* rl = rlb + mb * 4096;

    const int lane = t & 63, quad = lane >> 4, l15 = lane & 15, w = t >> 6;
    const int mw = (w >> 1) * 64;
    const int nw = (w & 1) * 64;
    const int mS = (w >> 1) * 64;
    const int nS = (w & 1) * 32;
    const int ksP = w & 1;

    load_lds16((const char*)Qg + (long)i0 * 64 + t * 16, (char*)Qs + (t >> 6) * 1024);
    load_lds16((const char*)Qg + (long)i0 * 64 + 4096 + t * 16,
               (char*)Qs + 4096 + (t >> 6) * 1024);

    float mlv[16], rlv[16];
#pragma unroll
    for (int fi = 0; fi < 4; ++fi)
#pragma unroll
        for (int r = 0; r < 4; ++r) {
            int i = i0 + mS + 16 * fi + quad * 4 + r;
            mlv[fi * 4 + r] = rm[i];
            rlv[fi * 4 + r] = rl[i];
        }

    f32x4 acc[4][4];
#pragma unroll
    for (int i = 0; i < 4; ++i)
#pragma unroll
        for (int j = 0; j < 4; ++j) acc[i][j] = (f32x4)0.f;
    const f32x4 zero4 = (f32x4)0.f;

    for (int j0 = jbase; j0 < jbase + 2048; j0 += 64) {
        __syncthreads();
        load_lds16((const char*)Kg + (long)j0 * 64 + t * 16, (char*)Ks + (t >> 6) * 1024);
#pragma unroll
        for (int ii = 0; ii < 4; ++ii) {
            int s = ii * 256 + t;
            int ks = s >> 9, cc = (s >> 2) & 127, blk = s & 3;
            load_lds16((const char*)Vg + (long)(c0 + cc) * 8192 + (j0 + ks * 32) * 2 + blk * 16,
                       (char*)Vs + ii * 4096 + (t >> 6) * 1024);
        }
        __syncthreads();

        bf16x8 qa[4], kb2[2];
#pragma unroll
        for (int fi = 0; fi < 4; ++fi)
            qa[fi] = *(const bf16x8*)((const char*)Qs + (mS + 16 * fi + l15) * 64 + quad * 16);
#pragma unroll
        for (int fj = 0; fj < 2; ++fj)
            kb2[fj] = *(const bf16x8*)((const char*)Ks + (nS + 16 * fj + l15) * 64 + quad * 16);
        f32x4 sA[4][2];
#pragma unroll
        for (int fi = 0; fi < 4; ++fi)
#pragma unroll
            for (int fj = 0; fj < 2; ++fj)
                sA[fi][fj] = __builtin_amdgcn_mfma_f32_16x16x32_bf16(
                    qa[fi], kb2[fj], zero4, 0, 0, 0);

        __bf16* prow = Ps + ksP * 4096;
#pragma unroll
        for (int fi = 0; fi < 4; ++fi)
#pragma unroll
            for (int fj = 0; fj < 2; ++fj) {
                int jl = 16 * fj + l15;
#pragma unroll
                for (int r = 0; r < 4; ++r) {
                    float p = __expf(sA[fi][fj][r] - mlv[fi * 4 + r]) * rlv[fi * 4 + r];
                    prow[(mS + 16 * fi + quad * 4 + r) * 32 + jl] = f2b(p);
                }
            }
        __syncthreads();

#pragma unroll
        for (int ks = 0; ks < 2; ++ks) {
            bf16x8 va[4], pb[4];
#pragma unroll
            for (int fi = 0; fi < 4; ++fi)
                va[fi] = *(const bf16x8*)((const char*)Vs + ks * 8192 +
                                          (mw + 16 * fi + l15) * 64 + quad * 16);
#pragma unroll
            for (int fj = 0; fj < 4; ++fj)
                pb[fj] = *(const bf16x8*)((const char*)Ps + ks * 8192 +
                                          (nw + 16 * fj + l15) * 64 + quad * 16);
#pragma unroll
            for (int fi = 0; fi < 4; ++fi)
#pragma unroll
                for (int fj = 0; fj < 4; ++fj)
                    acc[fi][fj] = __builtin_amdgcn_mfma_f32_16x16x32_bf16(
                        va[fi], pb[fj], acc[fi][fj], 0, 0, 0);
        }
    }

    // raw partial store
    float* pg = (seg ? part1 : part0) + (long)mb * 1048576;
#pragma unroll
    for (int fi = 0; fi < 4; ++fi) {
#pragma unroll
        for (int r = 0; r < 4; ++r) {
            int c = c0 + mw + 16 * fi + quad * 4 + r;
            float* zr = pg + (long)c * 4096;
#pragma unroll
            for (int fj = 0; fj < 4; ++fj) {
                int i = i0 + nw + 16 * fj + l15;
                zr[i] = acc[fi][fj][r];
            }
        }
    }
}

// ---------------------------------------------------------------------------
// z = gamma*(part0+part1) + conv, transposed bf16 store to Zt[pix][256].
// grid (128, 8, 4).
// ---------------------------------------------------------------------------
__global__ __launch_bounds__(256)
void zred_t(const float* __restrict__ p0, const float* __restrict__ p1,
            const float* __restrict__ convb, __bf16* __restrict__ Zt,
            const float* __restrict__ g_r, const float* __restrict__ g_d)
{
    __shared__ float tile[32][33];
    const int t = threadIdx.x;
    const int pix0 = blockIdx.x * 32;
    const int c0 = blockIdx.y * 32;
    const int mb = blockIdx.z;
    const int o = mb >> 1;
    const float gamma = (o ? g_d : g_r)[0];
    const long base = (long)mb * 1048576;

    int i = t >> 3, j4 = (t & 7) * 4;
    long row = base + (long)(c0 + i) * 4096 + pix0 + j4;
    float4 a = *(const float4*)&p0[row];
    float4 b = *(const float4*)&p1[row];
    float4 cv = *(const float4*)&convb[row];
    tile[i][j4 + 0] = gamma * (a.x + b.x) + cv.x;
    tile[i][j4 + 1] = gamma * (a.y + b.y) + cv.y;
    tile[i][j4 + 2] = gamma * (a.z + b.z) + cv.z;
    tile[i][j4 + 3] = gamma * (a.w + b.w) + cv.w;
    __syncthreads();
    int j = t >> 3, i4 = (t & 7) * 4;
    bf16x4 oq;
    oq.x = f2b(tile[i4 + 0][j]); oq.y = f2b(tile[i4 + 1][j]);
    oq.z = f2b(tile[i4 + 2][j]); oq.w = f2b(tile[i4 + 3][j]);
    *(bf16x4*)&Zt[(long)mb * NPIX * 256 + (long)(pix0 + j) * 256 + c0 + i4] = oq;
}

// ---------------------------------------------------------------------------
// Host launcher
// ---------------------------------------------------------------------------
// ws layout (float slots):
//   conv fp32 [4mb][256][4096] @ 0           (4,194,304)
//   part0 fp32 [4mb][256][4096]@ 4,194,304   (4,194,304)
//   rmb  [4mbo][4096]          @ 8,388,608   (16,384)
//   rlb                         @ 8,404,992  (16,384)
//   rmp  [2seg][4][4096]       @ 8,421,376   (32,768)
//   rlp                         @ 8,454,144  (32,768)
//   scA  [2][256]              @ 8,486,912   (512)
//   shB  [2][256]              @ 8,487,424   (512)
//   zrow (512 bf16)            @ 8,487,936   (256)
//   Wt   bf16 [2][9][256][512] @ 8,488,192   (1,179,648)
//   Xp   bf16 [4][4096][512]   @ 9,667,840   (4,194,304)  <- part1 after conv
//   Qt   bf16 [4][4096][32]    @ 13,862,144  (262,144)
//   Kt   bf16 [4][4096][32]    @ 14,124,288  (262,144)
//   Vbb  bf16 [4][256][4096]   @ 14,386,432  (2,097,152)
//   Ct   bf16 [4][4096][256]   @ 16,483,584  (2,097,152)
//   Zt   bf16 [4][4096][256]   @ 18,580,736  (2,097,152)
//   Wq   bf16 [2][128][256]    @ 20,677,888  (32,768)
//   Wk   bf16 [2][128][256]    @ 20,710,656  (32,768)
//   Wv   bf16 [2][256][256]    @ 20,743,424  (65,536)
//   Wu   bf16 [2][512][256]    @ 20,808,960  (131,072)
//   total 20,940,032 floats = 83.8 MiB
extern "C" void kernel_launch(void* const* d_in, const int* in_sizes, int n_in,
                              void* d_out, int out_size, void* d_ws, size_t ws_size,
                              hipStream_t stream)
{
    const float* in_rgb = (const float*)d_in[0];
    const float* in_dsm = (const float*)d_in[1];
    auto P = [&](int i) { return (const float*)d_in[i]; };

    float* ws    = (float*)d_ws;
    float* conv  = ws;
    float* part0 = ws + 4194304;
    float* rmb   = ws + 8388608;
    float* rlb   = ws + 8404992;
    float* rmp   = ws + 8421376;
    float* rlp   = ws + 8454144;
    float* scA   = ws + 8486912;
    float* shB   = ws + 8487424;
    __bf16* zrow = (__bf16*)(ws + 8487936);
    __bf16* Wt   = (__bf16*)(ws + 8488192);
    __bf16* Xp   = (__bf16*)(ws + 9667840);
    float*  part1 = ws + 9667840;            // aliases Xp (dead after conv)
    __bf16* Qt   = (__bf16*)(ws + 13862144);
    __bf16* Kt   = (__bf16*)(ws + 14124288);
    __bf16* Vbb  = (__bf16*)(ws + 14386432);
    __bf16* Ct   = (__bf16*)(ws + 16483584);
    __bf16* Zt   = (__bf16*)(ws + 18580736);
    __bf16* Wq   = (__bf16*)(ws + 20677888);
    __bf16* Wk   = (__bf16*)(ws + 20710656);
    __bf16* Wv   = (__bf16*)(ws + 20743424);
    __bf16* Wu   = (__bf16*)(ws + 20808960);

    // prep
    prep_w<<<2307, 256, 0, stream>>>(
        P(2), P(18), P(3), P(4), P(5), P(6), P(7),
        P(19), P(20), P(21), P(22), P(23),
        Wt, scA, shB, zrow);
    prep_gw<<<512, 256, 0, stream>>>(
        P(9), P(25), P(11), P(27), P(13), P(29), P(15), P(31),
        Wq, Wk, Wv, Wu);
    xpose<<<dim3(128, 16, 4), 256, 0, stream>>>(in_rgb, in_dsm, Xp);

    // conv3x3 + BN + PReLU (64-oc tiles, 512 blocks)
    conv_mfma<<<dim3(32, 4, 4), 256, 0, stream>>>(
        Wt, Xp, zrow, scA, shB, P(8), P(24), conv);
    t256<<<dim3(128, 8, 4), 256, 0, stream>>>(conv, Ct);

    // q/k/v projections
    proj_mfma<<<dim3(32, 1, 4), 256, 0, stream>>>(
        Wq, 32768, Ct, P(10), P(26), Qt, nullptr, nullptr, nullptr, nullptr, 0);
    proj_mfma<<<dim3(32, 1, 4), 256, 0, stream>>>(
        Wk, 32768, Ct, P(12), P(28), Kt, nullptr, nullptr, nullptr, nullptr, 0);
    proj_mfma<<<dim3(32, 2, 4), 256, 0, stream>>>(
        Wv, 65536, Ct, P(14), P(30), nullptr, Vbb, nullptr, nullptr, nullptr, 1);

    // softmax stats (j-split x2 + merge)
    attn_stats_mfma<<<dim3(32, 4, 2), 256, 0, stream>>>(Qt, Kt, rmp, rlp);
    stats_merge<<<64, 256, 0, stream>>>(rmp, rlp, rmb, rlb);

    // fused PV (j-split x2 -> raw partials; part1 overwrites dead Xp)
    attn_pv_mfma<<<dim3(32, 2, 8), 256, 0, stream>>>(
        Qt, Kt, Vbb, part0, part1, rmb, rlb);

    // z = gamma*(p0+p1)+conv, transpose + bf16 -> Zt
    zred_t<<<dim3(128, 8, 4), 256, 0, stream>>>(
        part0, part1, conv, Zt, P(17), P(33));

    // up projection + input residual -> fp32 out
    proj_mfma<<<dim3(32, 4, 4), 256, 0, stream>>>(
        Wu, 131072, Zt, P(16), P(32), nullptr, nullptr, (float*)d_out,
        in_rgb, in_dsm, 2);
}